// Round 3
// baseline (1390.388 us; speedup 1.0000x reference)
//
#include <hip/hip_runtime.h>
#include <hip/hip_fp16.h>

#define NN 40000
#define NE 640000
#define DF 128
#define NG 2000
#define NCH 157        // ceil(NN/256) node windows (256-node)
#define FILLB 625      // NE / (256*4) edge blocks, 4 edges/thread
#define G1_BLKS 313    // ceil(NN/128) -- GEMM 128-row tiles
#define NCHUNK 64      // edge chunks
#define ECH 10000      // NE / NCHUNK
#define NOCT 8         // node eighths
#define QN 5120        // nodes per eighth (window-aligned: 20 windows of 256)
#define NPAD (NOCT * QN)   // 40960 padded nodes
#define NWIN 160       // NPAD / 256 windows
#define HISTB (NCHUNK * NOCT)  // 512 hist blocks
#define NB 768         // persistent blocks: 3/CU guaranteed (LDS 35.9KB allows 4/CU)

typedef unsigned int u32;
typedef __attribute__((ext_vector_type(8))) short short8;
typedef __attribute__((ext_vector_type(4))) float floatx4;

// ---- bf16 helpers (packed u32: low 16 = even col, high = odd col) ----
__device__ inline float2 bf2_to_f2(u32 u) {
    return make_float2(__uint_as_float(u << 16), __uint_as_float(u & 0xffff0000u));
}
__device__ inline u32 f_to_bf(float f) {
    u32 u = __float_as_uint(f);
    return (u + 0x7fffu + ((u >> 16) & 1u)) >> 16;   // RNE
}
__device__ inline u32 pack_bf2(float a, float b) {
    return f_to_bf(a) | (f_to_bf(b) << 16);
}
__device__ inline float bf_to_f(short s) {
    return __uint_as_float(((u32)(unsigned short)s) << 16);
}
// packed col entry: low 16 = src index (<65536), high 16 = fp16(dis[src])
__device__ inline float colw_to_f(int cw) {
    return __half2float(__ushort_as_half((unsigned short)((u32)cw >> 16)));
}

// ---- grid barrier: monotone counter, agent scope; co-residency guaranteed by NB/launch_bounds ----
__device__ __forceinline__ void gsync(int* bar, int target) {
    __syncthreads();
    if (threadIdx.x == 0) {
        __threadfence();
        __hip_atomic_fetch_add(bar, 1, __ATOMIC_ACQ_REL, __HIP_MEMORY_SCOPE_AGENT);
        while (__hip_atomic_load(bar, __ATOMIC_ACQUIRE, __HIP_MEMORY_SCOPE_AGENT) < target)
            __builtin_amdgcn_s_sleep(2);
        __threadfence();
    }
    __syncthreads();
}

// ---------------- MFMA GEMM core (LDS passed in: uni 34816B union, sc/sh 128 floats) ----------------
template<bool BF16IN, bool FUSE_BN, bool WT_F32, bool TILE128>
__device__ __forceinline__ void gemm_core(const void* __restrict__ Xv, const void* __restrict__ wsrc,
                                          u32* __restrict__ outb, const float* __restrict__ slots,
                                          const float* __restrict__ gam, const float* __restrict__ bet,
                                          int bid, char* sbuf, float* sc, float* sh) {
    unsigned short* wlds = (unsigned short*)sbuf;
    unsigned short* clds = (unsigned short*)sbuf;
    int tid = threadIdx.x;
    int row0 = bid * (TILE128 ? 128 : 64);

    if (FUSE_BN) {
        if (tid < 128) {
            float s = 0.f, q = 0.f;
            for (int k = 0; k < 64; k++) {
                s += slots[k * 256 + tid];
                q += slots[k * 256 + 128 + tid];
            }
            const float inv_n = 1.0f / (float)NN;
            float mu = s * inv_n;
            float va = fmaf(-mu, mu, q * inv_n);
            float a = gam[tid] * rsqrtf(va + 1e-5f);
            sc[tid] = a;
            sh[tid] = fmaf(-mu, a, bet[tid]);
        }
    }
    if (WT_F32) {
        const float* W = (const float*)wsrc;     // W[k][c] row-major fp32
        for (int i = tid; i < 16384; i += 256) {
            int k = i >> 7, c = i & 127;
            wlds[c * 136 + k] = (unsigned short)f_to_bf(W[i]);
        }
    } else {
        const unsigned short* wt = (const unsigned short*)wsrc;   // pre-transposed bf16
        for (int i = tid; i < 2048; i += 256) {
            int c = i >> 4, s = i & 15;
            *(uint4*)&wlds[c * 136 + s * 8] = ((const uint4*)wt)[i];
        }
    }
    __syncthreads();

    int lane = tid & 63;
    int wave = tid >> 6;
    int qr = lane >> 4;
    int rl = lane & 15;

    if (TILE128) {
        int rA0 = row0 + wave * 32 + rl;
        int rA1 = rA0 + 16;
        int rA0c = rA0 < NN ? rA0 : NN - 1;
        int rA1c = rA1 < NN ? rA1 : NN - 1;
        floatx4 acc[2][8];
#pragma unroll
        for (int a = 0; a < 2; a++)
#pragma unroll
            for (int b = 0; b < 8; b++) acc[a][b] = (floatx4){0.f, 0.f, 0.f, 0.f};
#pragma unroll
        for (int kb = 0; kb < 4; kb++) {
            int k0 = kb * 32 + qr * 8;
            short8 a0, a1;
            if (!BF16IN) {
                const float* p0 = (const float*)Xv + (size_t)rA0c * DF + k0;
                const float* p1 = (const float*)Xv + (size_t)rA1c * DF + k0;
                float4 u0 = *(const float4*)p0, u1 = *(const float4*)(p0 + 4);
                float4 v0 = *(const float4*)p1, v1 = *(const float4*)(p1 + 4);
                float fa[8] = {u0.x, u0.y, u0.z, u0.w, u1.x, u1.y, u1.z, u1.w};
                float fb[8] = {v0.x, v0.y, v0.z, v0.w, v1.x, v1.y, v1.z, v1.w};
#pragma unroll
                for (int j = 0; j < 8; j++) { a0[j] = (short)f_to_bf(fa[j]); a1[j] = (short)f_to_bf(fb[j]); }
            } else {
                a0 = *(const short8*)((const u32*)Xv + (size_t)rA0c * 64 + (k0 >> 1));
                a1 = *(const short8*)((const u32*)Xv + (size_t)rA1c * 64 + (k0 >> 1));
                if (FUSE_BN) {
#pragma unroll
                    for (int j = 0; j < 8; j++) {
                        float f0 = fmaxf(fmaf(bf_to_f(a0[j]), sc[k0 + j], sh[k0 + j]), 0.f);
                        float f1 = fmaxf(fmaf(bf_to_f(a1[j]), sc[k0 + j], sh[k0 + j]), 0.f);
                        a0[j] = (short)f_to_bf(f0);
                        a1[j] = (short)f_to_bf(f1);
                    }
                }
            }
#pragma unroll
            for (int ct = 0; ct < 8; ct++) {
                short8 bfr = *(const short8*)&wlds[(ct * 16 + rl) * 136 + k0];
                acc[0][ct] = __builtin_amdgcn_mfma_f32_16x16x32_bf16(a0, bfr, acc[0][ct], 0, 0, 0);
                acc[1][ct] = __builtin_amdgcn_mfma_f32_16x16x32_bf16(a1, bfr, acc[1][ct], 0, 0, 0);
            }
        }
        __syncthreads();
#pragma unroll
        for (int rt = 0; rt < 2; rt++)
#pragma unroll
            for (int ct = 0; ct < 8; ct++)
#pragma unroll
                for (int r = 0; r < 4; r++) {
                    int lr = wave * 32 + rt * 16 + qr * 4 + r;
                    int c = ct * 16 + rl;
                    clds[lr * 136 + c] = (unsigned short)f_to_bf(acc[rt][ct][r]);
                }
        __syncthreads();
        for (int i = tid; i < 2048; i += 256) {
            int lr = i >> 4, s = i & 15;
            int grow = row0 + lr;
            if (grow < NN) {
                uint4 v = *(const uint4*)&clds[lr * 136 + s * 8];
                ((uint4*)(outb + (size_t)grow * 64))[s] = v;
            }
        }
    } else {
        int rA = row0 + wave * 16 + rl;
        floatx4 acc[8];
#pragma unroll
        for (int b = 0; b < 8; b++) acc[b] = (floatx4){0.f, 0.f, 0.f, 0.f};
#pragma unroll
        for (int kb = 0; kb < 4; kb++) {
            int k0 = kb * 32 + qr * 8;
            short8 a0;
            if (!BF16IN) {
                const float* p0 = (const float*)Xv + (size_t)rA * DF + k0;
                float4 u0 = *(const float4*)p0, u1 = *(const float4*)(p0 + 4);
                float fa[8] = {u0.x, u0.y, u0.z, u0.w, u1.x, u1.y, u1.z, u1.w};
#pragma unroll
                for (int j = 0; j < 8; j++) a0[j] = (short)f_to_bf(fa[j]);
            } else {
                a0 = *(const short8*)((const u32*)Xv + (size_t)rA * 64 + (k0 >> 1));
                if (FUSE_BN) {
#pragma unroll
                    for (int j = 0; j < 8; j++) {
                        float f0 = fmaxf(fmaf(bf_to_f(a0[j]), sc[k0 + j], sh[k0 + j]), 0.f);
                        a0[j] = (short)f_to_bf(f0);
                    }
                }
            }
#pragma unroll
            for (int ct = 0; ct < 8; ct++) {
                short8 bfr = *(const short8*)&wlds[(ct * 16 + rl) * 136 + k0];
                acc[ct] = __builtin_amdgcn_mfma_f32_16x16x32_bf16(a0, bfr, acc[ct], 0, 0, 0);
            }
        }
        __syncthreads();
#pragma unroll
        for (int ct = 0; ct < 8; ct++)
#pragma unroll
            for (int r = 0; r < 4; r++) {
                int lr = wave * 16 + qr * 4 + r;
                int c = ct * 16 + rl;
                clds[lr * 136 + c] = (unsigned short)f_to_bf(acc[ct][r]);
            }
        __syncthreads();
        for (int i = tid; i < 1024; i += 256) {
            int lr = i >> 4, s = i & 15;
            uint4 v = *(const uint4*)&clds[lr * 136 + s * 8];
            ((uint4*)(outb + (size_t)(row0 + lr) * 64))[s] = v;
        }
    }
}

// ---------------- gather: one wave/node, 4 nodes per virtual block; BN-stats fused ----------------
__device__ __forceinline__ void gather_quad(int vb, const u32* __restrict__ Hb, const int* __restrict__ row_ptr,
                                            const u32* __restrict__ col, const float* __restrict__ dis,
                                            const float* __restrict__ bias, u32* __restrict__ outb,
                                            float* __restrict__ slots, char* sbuf) {
    float (*sred)[128] = (float (*)[128])sbuf;
    float (*qred)[128] = (float (*)[128])(sbuf + 2048);
    int tid = threadIdx.x;
    int t = tid & 63;                       // lane: cols 2t, 2t+1
    int wv = tid >> 6;
    int node = vb * 4 + wv;
    float di = dis[node];
    int lo = row_ptr[node], hi = row_ptr[node + 1];
    float2 acc;
    {
        float2 a = bf2_to_f2(Hb[(size_t)node * 64 + t]);
        acc = make_float2(a.x * di, a.y * di);   // di factored: final acc *= di
    }
    for (int base = lo; base < hi; base += 64) {
        int m = hi - base; if (m > 64) m = 64;
        int cw = 0;
        if (t < m) cw = (int)col[base + t];
        int ng = (m + 3) >> 2;
        int c[4]; u32 u[4];
#pragma unroll
        for (int q = 0; q < 4; q++) {
            int idx = q < m ? q : 0;
            c[q] = __shfl(cw, idx);
            u[q] = Hb[(size_t)(c[q] & 0xffff) * 64 + t];
        }
        for (int g = 1; g < ng; g++) {
            int c2[4]; u32 u2[4];
#pragma unroll
            for (int q = 0; q < 4; q++) {
                int ii = g * 4 + q;
                int idx = ii < m ? ii : 0;
                c2[q] = __shfl(cw, idx);
                u2[q] = Hb[(size_t)(c2[q] & 0xffff) * 64 + t];
            }
#pragma unroll
            for (int q = 0; q < 4; q++) {
                int ii = (g - 1) * 4 + q;
                float wq = ii < m ? colw_to_f(c[q]) : 0.f;
                float2 h = bf2_to_f2(u[q]);
                acc.x = fmaf(h.x, wq, acc.x);
                acc.y = fmaf(h.y, wq, acc.y);
            }
#pragma unroll
            for (int q = 0; q < 4; q++) { c[q] = c2[q]; u[q] = u2[q]; }
        }
#pragma unroll
        for (int q = 0; q < 4; q++) {
            int ii = (ng - 1) * 4 + q;
            float wq = ii < m ? colw_to_f(c[q]) : 0.f;
            float2 h = bf2_to_f2(u[q]);
            acc.x = fmaf(h.x, wq, acc.x);
            acc.y = fmaf(h.y, wq, acc.y);
        }
    }
    float2 b = ((const float2*)bias)[t];
    acc.x = fmaf(acc.x, di, b.x);
    acc.y = fmaf(acc.y, di, b.y);
    outb[(size_t)node * 64 + t] = pack_bf2(acc.x, acc.y);
    __syncthreads();   // protect sred/qred reuse across grid-stride iterations
    sred[wv][2 * t] = acc.x;     sred[wv][2 * t + 1] = acc.y;
    qred[wv][2 * t] = acc.x * acc.x; qred[wv][2 * t + 1] = acc.y * acc.y;
    __syncthreads();
    if (tid < 128) {
        float s = sred[0][tid] + sred[1][tid] + sred[2][tid] + sred[3][tid];
        float q = qred[0][tid] + qred[1][tid] + qred[2][tid] + qred[3][tid];
        int slot = vb & 63;
        atomicAdd(&slots[slot * 256 + tid], s);
        atomicAdd(&slots[slot * 256 + 128 + tid], q);
    }
}

// ---------------- the fused persistent kernel: 7 phases, 6 grid barriers ----------------
__global__ __launch_bounds__(256, 3) void k_mega(
    const float* __restrict__ X, const int* __restrict__ src, const int* __restrict__ dst,
    const int* __restrict__ batch,
    const float* __restrict__ W1, const float* __restrict__ b1,
    const float* __restrict__ W2, const float* __restrict__ b2,
    const float* __restrict__ bn1g, const float* __restrict__ bn1b,
    const float* __restrict__ bn2g, const float* __restrict__ bn2b,
    const float* __restrict__ fc1w, const float* __restrict__ fc1b,
    const float* __restrict__ fc2w, const float* __restrict__ fc2b,
    const float* __restrict__ fc3w, const float* __restrict__ fc3b,
    int* __restrict__ degT, int* __restrict__ baseT, int* __restrict__ wsum,
    float* __restrict__ slots0, int* __restrict__ row_ptr, int* __restrict__ rank,
    u32* __restrict__ col, float* __restrict__ dis, unsigned short* __restrict__ wt2,
    u32* __restrict__ bufA, u32* __restrict__ bufB,
    int* bar, float* __restrict__ out)
{
    __shared__ __align__(16) char sbuf[34816];   // unioned across all phases
    __shared__ float sc[128], sh[128];
    int bid = blockIdx.x;
    int tid = threadIdx.x;
    float* slotsA = slots0;
    float* slotsB = slots0 + 64 * 256;

    // ---- phase 1: hist + slots-zero + wt2 + GEMM1 (828 virtual blocks, grid-stride) ----
    for (int vb = bid; vb < HISTB + 3 + G1_BLKS; vb += NB) {
        __syncthreads();   // sbuf reuse across vb iterations
        if (vb < HISTB) {
            int c = vb >> 3, oct = vb & 7;
            int nlo = oct * QN;
            int* hist = (int*)sbuf;
            for (int i = tid; i < QN; i += 256) hist[i] = 0;
            __syncthreads();
            int ebase = c * ECH;
            for (int i = tid; i < ECH; i += 256) {
                int d = dst[ebase + i];
                int tt = d - nlo;
                if ((u32)tt < (u32)QN) rank[ebase + i] = atomicAdd(&hist[tt], 1);
            }
            __syncthreads();
            for (int i = tid; i < QN; i += 256) degT[(size_t)c * NPAD + nlo + i] = hist[i];
            int wv = tid >> 6, lane = tid & 63;
            for (int lw = wv; lw < 20; lw += 4) {
                int v = hist[lw * 256 + lane] + hist[lw * 256 + 64 + lane]
                      + hist[lw * 256 + 128 + lane] + hist[lw * 256 + 192 + lane];
                for (int off = 32; off > 0; off >>= 1) v += __shfl_down(v, off);
                if (lane == 0) wsum[c * NWIN + oct * 20 + lw] = v;
            }
        } else if (vb < HISTB + 2) {
            float* s = slots0 + (size_t)(vb - HISTB) * 64 * 256;
            for (int i = tid; i < 64 * 256; i += 256) s[i] = 0.f;
        } else if (vb == HISTB + 2) {
            for (int i = tid; i < 128 * 128; i += 256) {
                int k = i >> 7, cc = i & 127;
                wt2[cc * 128 + k] = (unsigned short)f_to_bf(W2[i]);
            }
        } else {
            gemm_core<false, false, true, true>(X, W1, bufA, nullptr, nullptr, nullptr,
                                                vb - HISTB - 3, sbuf, sc, sh);
        }
    }
    gsync(bar, NB * 1);

    // ---- phase 2: scan (157 blocks) ----
    if (bid < NCH) {
        int* red = (int*)sbuf;
        int* ls  = (int*)(sbuf + 1024);
        int wnd = bid;
        int part = 0;
        int wp = tid < NWIN ? tid : tid - NWIN;   // tid % 160 for tid<256
        for (int idx = tid; idx < NCHUNK * NWIN; idx += 256) {
            if (wp < wnd) part += wsum[idx];
            wp += 96; if (wp >= NWIN) wp -= NWIN;  // 256 mod 160 = 96
        }
        red[tid] = part;
        int n = wnd * 256 + tid;    // < 40192 < NPAD, safe
        int run = 0;
#pragma unroll 4
        for (int c = 0; c < NCHUNK; c++) {
            int v = degT[(size_t)c * NPAD + n];
            baseT[(size_t)c * NPAD + n] = run;
            run += v;
        }
        int d = run;
        ls[tid] = d;
        __syncthreads();
#pragma unroll
        for (int off = 128; off > 0; off >>= 1) {
            if (tid < off) red[tid] += red[tid + off];
            __syncthreads();
        }
        int base = red[0];
#pragma unroll
        for (int off = 1; off < 256; off <<= 1) {
            int tv = (tid >= off) ? ls[tid - off] : 0;
            __syncthreads();
            ls[tid] += tv;
            __syncthreads();
        }
        if (n < NN) {
            int r = base + ls[tid] - d;   // global exclusive prefix
            row_ptr[n] = r;
            dis[n] = rsqrtf((float)(d + 1));
        }
        if (wnd == NCH - 1 && tid == 0) row_ptr[NN] = NE;
    }
    gsync(bar, NB * 2);

    // ---- phase 3: CSR fill (625 blocks) ----
    if (bid < FILLB) {
        int e0 = bid * 1024 + tid;
#pragma unroll
        for (int q = 0; q < 4; q++) {
            int e = e0 + q * 256;
            int d = dst[e];
            int s = src[e];
            int r = rank[e];
            int c = e / ECH;
            u32 h = (u32)__half_as_ushort(__float2half(dis[s]));
            col[row_ptr[d] + baseT[(size_t)c * NPAD + d] + r] = (u32)s | (h << 16);
        }
    }
    gsync(bar, NB * 3);

    // ---- phase 4: gather layer 1 (10000 virtual blocks) ----
    for (int vb = bid; vb < NN / 4; vb += NB)
        gather_quad(vb, bufA, row_ptr, col, dis, b1, bufB, slotsA, sbuf);
    gsync(bar, NB * 4);

    // ---- phase 5: GEMM2 + fused BN1/ReLU (313 blocks) ----
    if (bid < G1_BLKS)
        gemm_core<true, true, false, true>(bufB, wt2, bufA, slotsA, bn1g, bn1b, bid, sbuf, sc, sh);
    gsync(bar, NB * 5);

    // ---- phase 6: gather layer 2 ----
    for (int vb = bid; vb < NN / 4; vb += NB)
        gather_quad(vb, bufA, row_ptr, col, dis, b2, bufB, slotsB, sbuf);
    gsync(bar, NB * 6);

    // ---- phase 7: pool (BN2+ReLU) + fc1 + fc2 + fc3 (500 blocks) ----
    if (bid < NG / 4) {
        float (*pooled)[128] = (float (*)[128])sbuf;
        float (*g1)[256] = (float (*)[256])(sbuf + 2048);
        float (*g2)[256] = (float (*)[256])(sbuf + 2048 + 4096);
        int* bnds = (int*)(sbuf + 2048 + 8192);
        int gbase = bid * 4;
        if (tid < 128) {
            float s = 0.f, q = 0.f;
            for (int k = 0; k < 64; k++) {
                s += slotsB[k * 256 + tid];
                q += slotsB[k * 256 + 128 + tid];
            }
            const float inv_n = 1.0f / (float)NN;
            float mu = s * inv_n;
            float va = fmaf(-mu, mu, q * inv_n);
            float a = bn2g[tid] * rsqrtf(va + 1e-5f);
            sc[tid] = a;
            sh[tid] = fmaf(-mu, a, bn2b[tid]);
        } else if (tid < 133) {
            int target = gbase + (tid - 128);
            int a = 0, b = NN;
            while (a < b) { int m = (a + b) >> 1; if (batch[m] < target) a = m + 1; else b = m; }
            bnds[tid - 128] = a;
        }
        __syncthreads();
        {
            int g = tid >> 6, p = tid & 63;
            int lo = bnds[g], hi = bnds[g + 1];
            float a0 = 0.f, a1 = 0.f;
            float sc0 = sc[2 * p], sh0 = sh[2 * p], sc1 = sc[2 * p + 1], sh1 = sh[2 * p + 1];
            for (int i = lo; i < hi; i++) {
                float2 v = bf2_to_f2(bufB[(size_t)i * 64 + p]);
                a0 += fmaxf(fmaf(v.x, sc0, sh0), 0.f);
                a1 += fmaxf(fmaf(v.y, sc1, sh1), 0.f);
            }
            pooled[g][2 * p] = a0;
            pooled[g][2 * p + 1] = a1;
        }
        __syncthreads();
        {
            float x0 = 0.f, x1 = 0.f, x2 = 0.f, x3 = 0.f;
            for (int k = 0; k < 128; k++) {
                float wv = fc1w[k * 256 + tid];
                x0 = fmaf(pooled[0][k], wv, x0);
                x1 = fmaf(pooled[1][k], wv, x1);
                x2 = fmaf(pooled[2][k], wv, x2);
                x3 = fmaf(pooled[3][k], wv, x3);
            }
            float bb = fc1b[tid];
            g1[0][tid] = fmaxf(x0 + bb, 0.f);
            g1[1][tid] = fmaxf(x1 + bb, 0.f);
            g1[2][tid] = fmaxf(x2 + bb, 0.f);
            g1[3][tid] = fmaxf(x3 + bb, 0.f);
        }
        __syncthreads();
        {
            float x0 = 0.f, x1 = 0.f, x2 = 0.f, x3 = 0.f;
            for (int k = 0; k < 256; k++) {
                float wv = fc2w[k * 256 + tid];
                x0 = fmaf(g1[0][k], wv, x0);
                x1 = fmaf(g1[1][k], wv, x1);
                x2 = fmaf(g1[2][k], wv, x2);
                x3 = fmaf(g1[3][k], wv, x3);
            }
            float bb = fc2b[tid];
            g2[0][tid] = fmaxf(x0 + bb, 0.f);
            g2[1][tid] = fmaxf(x1 + bb, 0.f);
            g2[2][tid] = fmaxf(x2 + bb, 0.f);
            g2[3][tid] = fmaxf(x3 + bb, 0.f);
        }
        __syncthreads();
        {
            int lane = tid & 63, wv = tid >> 6;
            float s = fmaf(g2[wv][lane], fc3w[lane],
                      fmaf(g2[wv][64 + lane], fc3w[64 + lane],
                      fmaf(g2[wv][128 + lane], fc3w[128 + lane],
                           g2[wv][192 + lane] * fc3w[192 + lane])));
            for (int off = 32; off > 0; off >>= 1) s += __shfl_down(s, off);
            if (lane == 0) out[gbase + wv] = s + fc3b[0];
        }
    }
}

extern "C" void kernel_launch(void* const* d_in, const int* in_sizes, int n_in,
                              void* d_out, int out_size, void* d_ws, size_t ws_size,
                              hipStream_t stream) {
    const float* x    = (const float*)d_in[0];
    const int*   ei   = (const int*)d_in[1];
    const int*   batch= (const int*)d_in[2];
    const float* W1   = (const float*)d_in[4];
    const float* b1   = (const float*)d_in[5];
    const float* W2   = (const float*)d_in[6];
    const float* b2   = (const float*)d_in[7];
    const float* bn1g = (const float*)d_in[8];
    const float* bn1b = (const float*)d_in[9];
    const float* bn2g = (const float*)d_in[10];
    const float* bn2b = (const float*)d_in[11];
    const float* fc1w = (const float*)d_in[12];
    const float* fc1b = (const float*)d_in[13];
    const float* fc2w = (const float*)d_in[14];
    const float* fc2b = (const float*)d_in[15];
    const float* fc3w = (const float*)d_in[16];
    const float* fc3b = (const float*)d_in[17];
    const int* src = ei;
    const int* dst = ei + NE;
    float* outp = (float*)d_out;

    char* w = (char*)d_ws;
    size_t o = 0;
    auto alloc = [&](size_t bytes) -> char* {
        char* p = w + o;
        o = (o + bytes + 255) & ~(size_t)255;
        return p;
    };
    int*   degT    = (int*)alloc((size_t)NCHUNK * NPAD * 4);   // written fully, no zeroing
    int*   baseT   = (int*)alloc((size_t)NCHUNK * NPAD * 4);
    int*   wsum    = (int*)alloc((size_t)NCHUNK * NWIN * 4);
    float* slots0  = (float*)alloc((size_t)2 * 64 * 256 * 4);  // zeroed in phase 1
    int*   row_ptr = (int*)alloc((size_t)(NN + 1) * 4);
    int*   rank    = (int*)alloc((size_t)NE * 4);
    u32*   col     = (u32*)alloc((size_t)NE * 4);
    float* dis     = (float*)alloc((size_t)NN * 4);
    unsigned short* wt2 = (unsigned short*)alloc(128 * 128 * 2);
    u32*   bufA    = (u32*)alloc((size_t)NN * 64 * 4);
    u32*   bufB    = (u32*)alloc((size_t)NN * 64 * 4);
    int*   bar     = (int*)alloc(256);

    hipMemsetAsync(bar, 0, 256, stream);
    k_mega<<<NB, 256, 0, stream>>>(x, src, dst, batch, W1, b1, W2, b2,
                                   bn1g, bn1b, bn2g, bn2b,
                                   fc1w, fc1b, fc2w, fc2b, fc3w, fc3b,
                                   degT, baseT, wsum, slots0, row_ptr, rank,
                                   col, dis, wt2, bufA, bufB, bar, outp);
}

// Round 4
// 793.819 us; speedup vs baseline: 1.7515x; 1.7515x over previous
//
#include <hip/hip_runtime.h>
#include <hip/hip_fp16.h>

#define NN 40000
#define NE 640000
#define DF 128
#define NG 2000
#define NCH 157        // ceil(NN/256) node windows (256-node)
#define FILLB 625      // NE / (256*4) edge blocks, 4 edges/thread
#define G1_BLKS 313    // ceil(NN/128) -- GEMM 128-row tiles
#define G2_BLKS 625    // NN/64 -- GEMM2 64-row tiles (fused phase 5: better spread)
#define NCHUNK 64      // edge chunks
#define ECH 10000      // NE / NCHUNK
#define NOCT 8         // node eighths
#define QN 5120        // nodes per eighth (window-aligned: 20 windows of 256)
#define NPAD (NOCT * QN)   // 40960 padded nodes
#define NWIN 160       // NPAD / 256 windows
#define HISTB (NCHUNK * NOCT)  // 512 hist blocks
#define NB 768         // persistent blocks: 3/CU guaranteed (proven resident in round 3)

typedef unsigned int u32;
typedef __attribute__((ext_vector_type(8))) short short8;
typedef __attribute__((ext_vector_type(4))) float floatx4;

// ---- bf16 helpers (packed u32: low 16 = even col, high = odd col) ----
__device__ inline float2 bf2_to_f2(u32 u) {
    return make_float2(__uint_as_float(u << 16), __uint_as_float(u & 0xffff0000u));
}
__device__ inline u32 f_to_bf(float f) {
    u32 u = __float_as_uint(f);
    return (u + 0x7fffu + ((u >> 16) & 1u)) >> 16;   // RNE
}
__device__ inline u32 pack_bf2(float a, float b) {
    return f_to_bf(a) | (f_to_bf(b) << 16);
}
__device__ inline float bf_to_f(short s) {
    return __uint_as_float(((u32)(unsigned short)s) << 16);
}
// packed col entry: low 16 = src index (<65536), high 16 = fp16(dis[src])
__device__ inline float colw_to_f(int cw) {
    return __half2float(__ushort_as_half((unsigned short)((u32)cw >> 16)));
}

// ---- grid barrier: RELAXED polls (no per-poll cache maintenance!), single release/acquire
// fences. Round-3 lesson: ACQUIRE-poll at agent scope emits cache-invalidates every
// iteration -> L2 invalidate storm -> 5x global slowdown. Relaxed agent-scope atomic
// load reads the coherent point without maintenance ops.
__device__ __forceinline__ void gsync(int* bar, int target) {
    __syncthreads();
    if (threadIdx.x == 0) {
        __threadfence();   // release: make this block's phase writes visible (once)
        __hip_atomic_fetch_add(bar, 1, __ATOMIC_RELAXED, __HIP_MEMORY_SCOPE_AGENT);
        while (__hip_atomic_load(bar, __ATOMIC_RELAXED, __HIP_MEMORY_SCOPE_AGENT) < target)
            __builtin_amdgcn_s_sleep(2);
        __threadfence();   // acquire: invalidate stale lines (once, after spin exits)
    }
    __syncthreads();
}

// ---------------- MFMA GEMM core (LDS passed in: uni 34816B union, sc/sh 128 floats) ----------------
template<bool BF16IN, bool FUSE_BN, bool WT_F32, bool TILE128>
__device__ __forceinline__ void gemm_core(const void* __restrict__ Xv, const void* __restrict__ wsrc,
                                          u32* __restrict__ outb, const float* __restrict__ slots,
                                          const float* __restrict__ gam, const float* __restrict__ bet,
                                          int bid, char* sbuf, float* sc, float* sh) {
    unsigned short* wlds = (unsigned short*)sbuf;
    unsigned short* clds = (unsigned short*)sbuf;
    int tid = threadIdx.x;
    int row0 = bid * (TILE128 ? 128 : 64);

    if (FUSE_BN) {
        if (tid < 128) {
            float s = 0.f, q = 0.f;
            for (int k = 0; k < 64; k++) {
                s += slots[k * 256 + tid];
                q += slots[k * 256 + 128 + tid];
            }
            const float inv_n = 1.0f / (float)NN;
            float mu = s * inv_n;
            float va = fmaf(-mu, mu, q * inv_n);
            float a = gam[tid] * rsqrtf(va + 1e-5f);
            sc[tid] = a;
            sh[tid] = fmaf(-mu, a, bet[tid]);
        }
    }
    if (WT_F32) {
        const float* W = (const float*)wsrc;     // W[k][c] row-major fp32
        for (int i = tid; i < 16384; i += 256) {
            int k = i >> 7, c = i & 127;
            wlds[c * 136 + k] = (unsigned short)f_to_bf(W[i]);
        }
    } else {
        const unsigned short* wt = (const unsigned short*)wsrc;   // pre-transposed bf16
        for (int i = tid; i < 2048; i += 256) {
            int c = i >> 4, s = i & 15;
            *(uint4*)&wlds[c * 136 + s * 8] = ((const uint4*)wt)[i];
        }
    }
    __syncthreads();

    int lane = tid & 63;
    int wave = tid >> 6;
    int qr = lane >> 4;
    int rl = lane & 15;

    if (TILE128) {
        int rA0 = row0 + wave * 32 + rl;
        int rA1 = rA0 + 16;
        int rA0c = rA0 < NN ? rA0 : NN - 1;
        int rA1c = rA1 < NN ? rA1 : NN - 1;
        floatx4 acc[2][8];
#pragma unroll
        for (int a = 0; a < 2; a++)
#pragma unroll
            for (int b = 0; b < 8; b++) acc[a][b] = (floatx4){0.f, 0.f, 0.f, 0.f};
#pragma unroll
        for (int kb = 0; kb < 4; kb++) {
            int k0 = kb * 32 + qr * 8;
            short8 a0, a1;
            if (!BF16IN) {
                const float* p0 = (const float*)Xv + (size_t)rA0c * DF + k0;
                const float* p1 = (const float*)Xv + (size_t)rA1c * DF + k0;
                float4 u0 = *(const float4*)p0, u1 = *(const float4*)(p0 + 4);
                float4 v0 = *(const float4*)p1, v1 = *(const float4*)(p1 + 4);
                float fa[8] = {u0.x, u0.y, u0.z, u0.w, u1.x, u1.y, u1.z, u1.w};
                float fb[8] = {v0.x, v0.y, v0.z, v0.w, v1.x, v1.y, v1.z, v1.w};
#pragma unroll
                for (int j = 0; j < 8; j++) { a0[j] = (short)f_to_bf(fa[j]); a1[j] = (short)f_to_bf(fb[j]); }
            } else {
                a0 = *(const short8*)((const u32*)Xv + (size_t)rA0c * 64 + (k0 >> 1));
                a1 = *(const short8*)((const u32*)Xv + (size_t)rA1c * 64 + (k0 >> 1));
                if (FUSE_BN) {
#pragma unroll
                    for (int j = 0; j < 8; j++) {
                        float f0 = fmaxf(fmaf(bf_to_f(a0[j]), sc[k0 + j], sh[k0 + j]), 0.f);
                        float f1 = fmaxf(fmaf(bf_to_f(a1[j]), sc[k0 + j], sh[k0 + j]), 0.f);
                        a0[j] = (short)f_to_bf(f0);
                        a1[j] = (short)f_to_bf(f1);
                    }
                }
            }
#pragma unroll
            for (int ct = 0; ct < 8; ct++) {
                short8 bfr = *(const short8*)&wlds[(ct * 16 + rl) * 136 + k0];
                acc[0][ct] = __builtin_amdgcn_mfma_f32_16x16x32_bf16(a0, bfr, acc[0][ct], 0, 0, 0);
                acc[1][ct] = __builtin_amdgcn_mfma_f32_16x16x32_bf16(a1, bfr, acc[1][ct], 0, 0, 0);
            }
        }
        __syncthreads();
#pragma unroll
        for (int rt = 0; rt < 2; rt++)
#pragma unroll
            for (int ct = 0; ct < 8; ct++)
#pragma unroll
                for (int r = 0; r < 4; r++) {
                    int lr = wave * 32 + rt * 16 + qr * 4 + r;
                    int c = ct * 16 + rl;
                    clds[lr * 136 + c] = (unsigned short)f_to_bf(acc[rt][ct][r]);
                }
        __syncthreads();
        for (int i = tid; i < 2048; i += 256) {
            int lr = i >> 4, s = i & 15;
            int grow = row0 + lr;
            if (grow < NN) {
                uint4 v = *(const uint4*)&clds[lr * 136 + s * 8];
                ((uint4*)(outb + (size_t)grow * 64))[s] = v;
            }
        }
    } else {
        int rA = row0 + wave * 16 + rl;
        floatx4 acc[8];
#pragma unroll
        for (int b = 0; b < 8; b++) acc[b] = (floatx4){0.f, 0.f, 0.f, 0.f};
#pragma unroll
        for (int kb = 0; kb < 4; kb++) {
            int k0 = kb * 32 + qr * 8;
            short8 a0;
            if (!BF16IN) {
                const float* p0 = (const float*)Xv + (size_t)rA * DF + k0;
                float4 u0 = *(const float4*)p0, u1 = *(const float4*)(p0 + 4);
                float fa[8] = {u0.x, u0.y, u0.z, u0.w, u1.x, u1.y, u1.z, u1.w};
#pragma unroll
                for (int j = 0; j < 8; j++) a0[j] = (short)f_to_bf(fa[j]);
            } else {
                a0 = *(const short8*)((const u32*)Xv + (size_t)rA * 64 + (k0 >> 1));
                if (FUSE_BN) {
#pragma unroll
                    for (int j = 0; j < 8; j++) {
                        float f0 = fmaxf(fmaf(bf_to_f(a0[j]), sc[k0 + j], sh[k0 + j]), 0.f);
                        a0[j] = (short)f_to_bf(f0);
                    }
                }
            }
#pragma unroll
            for (int ct = 0; ct < 8; ct++) {
                short8 bfr = *(const short8*)&wlds[(ct * 16 + rl) * 136 + k0];
                acc[ct] = __builtin_amdgcn_mfma_f32_16x16x32_bf16(a0, bfr, acc[ct], 0, 0, 0);
            }
        }
        __syncthreads();
#pragma unroll
        for (int ct = 0; ct < 8; ct++)
#pragma unroll
            for (int r = 0; r < 4; r++) {
                int lr = wave * 16 + qr * 4 + r;
                int c = ct * 16 + rl;
                clds[lr * 136 + c] = (unsigned short)f_to_bf(acc[ct][r]);
            }
        __syncthreads();
        for (int i = tid; i < 1024; i += 256) {
            int lr = i >> 4, s = i & 15;
            uint4 v = *(const uint4*)&clds[lr * 136 + s * 8];
            ((uint4*)(outb + (size_t)(row0 + lr) * 64))[s] = v;
        }
    }
}

// ---------------- gather: one wave/node, 4 nodes per virtual block; BN-stats fused ----------------
__device__ __forceinline__ void gather_quad(int vb, const u32* __restrict__ Hb, const int* __restrict__ row_ptr,
                                            const u32* __restrict__ col, const float* __restrict__ dis,
                                            const float* __restrict__ bias, u32* __restrict__ outb,
                                            float* __restrict__ slots, char* sbuf) {
    float (*sred)[128] = (float (*)[128])sbuf;
    float (*qred)[128] = (float (*)[128])(sbuf + 2048);
    int tid = threadIdx.x;
    int t = tid & 63;                       // lane: cols 2t, 2t+1
    int wv = tid >> 6;
    int node = vb * 4 + wv;
    float di = dis[node];
    int lo = row_ptr[node], hi = row_ptr[node + 1];
    float2 acc;
    {
        float2 a = bf2_to_f2(Hb[(size_t)node * 64 + t]);
        acc = make_float2(a.x * di, a.y * di);   // di factored: final acc *= di
    }
    for (int base = lo; base < hi; base += 64) {
        int m = hi - base; if (m > 64) m = 64;
        int cw = 0;
        if (t < m) cw = (int)col[base + t];
        int ng = (m + 3) >> 2;
        int c[4]; u32 u[4];
#pragma unroll
        for (int q = 0; q < 4; q++) {
            int idx = q < m ? q : 0;
            c[q] = __shfl(cw, idx);
            u[q] = Hb[(size_t)(c[q] & 0xffff) * 64 + t];
        }
        for (int g = 1; g < ng; g++) {
            int c2[4]; u32 u2[4];
#pragma unroll
            for (int q = 0; q < 4; q++) {
                int ii = g * 4 + q;
                int idx = ii < m ? ii : 0;
                c2[q] = __shfl(cw, idx);
                u2[q] = Hb[(size_t)(c2[q] & 0xffff) * 64 + t];
            }
#pragma unroll
            for (int q = 0; q < 4; q++) {
                int ii = (g - 1) * 4 + q;
                float wq = ii < m ? colw_to_f(c[q]) : 0.f;
                float2 h = bf2_to_f2(u[q]);
                acc.x = fmaf(h.x, wq, acc.x);
                acc.y = fmaf(h.y, wq, acc.y);
            }
#pragma unroll
            for (int q = 0; q < 4; q++) { c[q] = c2[q]; u[q] = u2[q]; }
        }
#pragma unroll
        for (int q = 0; q < 4; q++) {
            int ii = (ng - 1) * 4 + q;
            float wq = ii < m ? colw_to_f(c[q]) : 0.f;
            float2 h = bf2_to_f2(u[q]);
            acc.x = fmaf(h.x, wq, acc.x);
            acc.y = fmaf(h.y, wq, acc.y);
        }
    }
    float2 b = ((const float2*)bias)[t];
    acc.x = fmaf(acc.x, di, b.x);
    acc.y = fmaf(acc.y, di, b.y);
    outb[(size_t)node * 64 + t] = pack_bf2(acc.x, acc.y);
    __syncthreads();   // protect sred/qred reuse across grid-stride iterations
    sred[wv][2 * t] = acc.x;     sred[wv][2 * t + 1] = acc.y;
    qred[wv][2 * t] = acc.x * acc.x; qred[wv][2 * t + 1] = acc.y * acc.y;
    __syncthreads();
    if (tid < 128) {
        float s = sred[0][tid] + sred[1][tid] + sred[2][tid] + sred[3][tid];
        float q = qred[0][tid] + qred[1][tid] + qred[2][tid] + qred[3][tid];
        int slot = vb & 63;
        atomicAdd(&slots[slot * 256 + tid], s);
        atomicAdd(&slots[slot * 256 + 128 + tid], q);
    }
}

// ---------------- the fused persistent kernel: 7 phases, 6 grid barriers ----------------
__global__ __launch_bounds__(256, 3) void k_mega(
    const float* __restrict__ X, const int* __restrict__ src, const int* __restrict__ dst,
    const int* __restrict__ batch,
    const float* __restrict__ W1, const float* __restrict__ b1,
    const float* __restrict__ W2, const float* __restrict__ b2,
    const float* __restrict__ bn1g, const float* __restrict__ bn1b,
    const float* __restrict__ bn2g, const float* __restrict__ bn2b,
    const float* __restrict__ fc1w, const float* __restrict__ fc1b,
    const float* __restrict__ fc2w, const float* __restrict__ fc2b,
    const float* __restrict__ fc3w, const float* __restrict__ fc3b,
    int* __restrict__ degT, int* __restrict__ baseT, int* __restrict__ wsum,
    float* __restrict__ slots0, int* __restrict__ row_ptr, int* __restrict__ rank,
    u32* __restrict__ col, float* __restrict__ dis, unsigned short* __restrict__ wt2,
    u32* __restrict__ bufA, u32* __restrict__ bufB,
    int* bar, float* __restrict__ out)
{
    __shared__ __align__(16) char sbuf[34816];   // unioned across all phases
    __shared__ float sc[128], sh[128];
    int bid = blockIdx.x;
    int tid = threadIdx.x;
    float* slotsA = slots0;
    float* slotsB = slots0 + 64 * 256;

    // ---- phase 1: hist + slots-zero + wt2 + GEMM1 (828 virtual blocks, grid-stride) ----
    for (int vb = bid; vb < HISTB + 3 + G1_BLKS; vb += NB) {
        __syncthreads();   // sbuf reuse across vb iterations
        if (vb < HISTB) {
            int c = vb >> 3, oct = vb & 7;
            int nlo = oct * QN;
            int* hist = (int*)sbuf;
            for (int i = tid; i < QN; i += 256) hist[i] = 0;
            __syncthreads();
            int ebase = c * ECH;
            const int4* dst4 = (const int4*)(dst + ebase);   // ECH=10000 = 2500 int4s
            for (int i4 = tid; i4 < 2500; i4 += 256) {
                int4 d4 = dst4[i4];
                int e = ebase + i4 * 4;
                int t0 = d4.x - nlo, t1 = d4.y - nlo, t2 = d4.z - nlo, t3 = d4.w - nlo;
                if ((u32)t0 < (u32)QN) rank[e]     = atomicAdd(&hist[t0], 1);
                if ((u32)t1 < (u32)QN) rank[e + 1] = atomicAdd(&hist[t1], 1);
                if ((u32)t2 < (u32)QN) rank[e + 2] = atomicAdd(&hist[t2], 1);
                if ((u32)t3 < (u32)QN) rank[e + 3] = atomicAdd(&hist[t3], 1);
            }
            __syncthreads();
            for (int i = tid; i < QN; i += 256) degT[(size_t)c * NPAD + nlo + i] = hist[i];
            int wv = tid >> 6, lane = tid & 63;
            for (int lw = wv; lw < 20; lw += 4) {
                int v = hist[lw * 256 + lane] + hist[lw * 256 + 64 + lane]
                      + hist[lw * 256 + 128 + lane] + hist[lw * 256 + 192 + lane];
                for (int off = 32; off > 0; off >>= 1) v += __shfl_down(v, off);
                if (lane == 0) wsum[c * NWIN + oct * 20 + lw] = v;
            }
        } else if (vb < HISTB + 2) {
            float* s = slots0 + (size_t)(vb - HISTB) * 64 * 256;
            for (int i = tid; i < 64 * 256; i += 256) s[i] = 0.f;
        } else if (vb == HISTB + 2) {
            for (int i = tid; i < 128 * 128; i += 256) {
                int k = i >> 7, cc = i & 127;
                wt2[cc * 128 + k] = (unsigned short)f_to_bf(W2[i]);
            }
        } else {
            gemm_core<false, false, true, true>(X, W1, bufA, nullptr, nullptr, nullptr,
                                                vb - HISTB - 3, sbuf, sc, sh);
        }
    }
    gsync(bar, NB * 1);

    // ---- phase 2: scan (157 blocks) ----
    if (bid < NCH) {
        int* red = (int*)sbuf;
        int* ls  = (int*)(sbuf + 1024);
        int wnd = bid;
        int part = 0;
        int wp = tid < NWIN ? tid : tid - NWIN;   // tid % 160 for tid<256
        for (int idx = tid; idx < NCHUNK * NWIN; idx += 256) {
            if (wp < wnd) part += wsum[idx];
            wp += 96; if (wp >= NWIN) wp -= NWIN;  // 256 mod 160 = 96
        }
        red[tid] = part;
        int n = wnd * 256 + tid;    // < 40192 < NPAD, safe
        int run = 0;
#pragma unroll 4
        for (int c = 0; c < NCHUNK; c++) {
            int v = degT[(size_t)c * NPAD + n];
            baseT[(size_t)c * NPAD + n] = run;
            run += v;
        }
        int d = run;
        ls[tid] = d;
        __syncthreads();
#pragma unroll
        for (int off = 128; off > 0; off >>= 1) {
            if (tid < off) red[tid] += red[tid + off];
            __syncthreads();
        }
        int base = red[0];
#pragma unroll
        for (int off = 1; off < 256; off <<= 1) {
            int tv = (tid >= off) ? ls[tid - off] : 0;
            __syncthreads();
            ls[tid] += tv;
            __syncthreads();
        }
        if (n < NN) {
            int r = base + ls[tid] - d;   // global exclusive prefix
            row_ptr[n] = r;
            dis[n] = rsqrtf((float)(d + 1));
        }
        if (wnd == NCH - 1 && tid == 0) row_ptr[NN] = NE;
    }
    gsync(bar, NB * 2);

    // ---- phase 3: CSR fill (625 blocks) ----
    if (bid < FILLB) {
        int e0 = bid * 1024 + tid;
#pragma unroll
        for (int q = 0; q < 4; q++) {
            int e = e0 + q * 256;
            int d = dst[e];
            int s = src[e];
            int r = rank[e];
            int c = e / ECH;
            u32 h = (u32)__half_as_ushort(__float2half(dis[s]));
            col[row_ptr[d] + baseT[(size_t)c * NPAD + d] + r] = (u32)s | (h << 16);
        }
    }
    gsync(bar, NB * 3);

    // ---- phase 4: gather layer 1 (10000 virtual blocks) ----
    for (int vb = bid; vb < NN / 4; vb += NB)
        gather_quad(vb, bufA, row_ptr, col, dis, b1, bufB, slotsA, sbuf);
    gsync(bar, NB * 4);

    // ---- phase 5: GEMM2 + fused BN1/ReLU (625 x 64-row tiles: better spread over 768 blocks) ----
    if (bid < G2_BLKS)
        gemm_core<true, true, false, false>(bufB, wt2, bufA, slotsA, bn1g, bn1b, bid, sbuf, sc, sh);
    gsync(bar, NB * 5);

    // ---- phase 6: gather layer 2 ----
    for (int vb = bid; vb < NN / 4; vb += NB)
        gather_quad(vb, bufA, row_ptr, col, dis, b2, bufB, slotsB, sbuf);
    gsync(bar, NB * 6);

    // ---- phase 7: pool (BN2+ReLU) + fc1 + fc2 + fc3 (500 blocks) ----
    if (bid < NG / 4) {
        float (*pooled)[128] = (float (*)[128])sbuf;
        float (*g1)[256] = (float (*)[256])(sbuf + 2048);
        float (*g2)[256] = (float (*)[256])(sbuf + 2048 + 4096);
        int* bnds = (int*)(sbuf + 2048 + 8192);
        int gbase = bid * 4;
        if (tid < 128) {
            float s = 0.f, q = 0.f;
            for (int k = 0; k < 64; k++) {
                s += slotsB[k * 256 + tid];
                q += slotsB[k * 256 + 128 + tid];
            }
            const float inv_n = 1.0f / (float)NN;
            float mu = s * inv_n;
            float va = fmaf(-mu, mu, q * inv_n);
            float a = bn2g[tid] * rsqrtf(va + 1e-5f);
            sc[tid] = a;
            sh[tid] = fmaf(-mu, a, bn2b[tid]);
        } else if (tid < 133) {
            int target = gbase + (tid - 128);
            int a = 0, b = NN;
            while (a < b) { int m = (a + b) >> 1; if (batch[m] < target) a = m + 1; else b = m; }
            bnds[tid - 128] = a;
        }
        __syncthreads();
        {
            int g = tid >> 6, p = tid & 63;
            int lo = bnds[g], hi = bnds[g + 1];
            float a0 = 0.f, a1 = 0.f;
            float sc0 = sc[2 * p], sh0 = sh[2 * p], sc1 = sc[2 * p + 1], sh1 = sh[2 * p + 1];
            for (int i = lo; i < hi; i++) {
                float2 v = bf2_to_f2(bufB[(size_t)i * 64 + p]);
                a0 += fmaxf(fmaf(v.x, sc0, sh0), 0.f);
                a1 += fmaxf(fmaf(v.y, sc1, sh1), 0.f);
            }
            pooled[g][2 * p] = a0;
            pooled[g][2 * p + 1] = a1;
        }
        __syncthreads();
        {
            float x0 = 0.f, x1 = 0.f, x2 = 0.f, x3 = 0.f;
            for (int k = 0; k < 128; k++) {
                float wv = fc1w[k * 256 + tid];
                x0 = fmaf(pooled[0][k], wv, x0);
                x1 = fmaf(pooled[1][k], wv, x1);
                x2 = fmaf(pooled[2][k], wv, x2);
                x3 = fmaf(pooled[3][k], wv, x3);
            }
            float bb = fc1b[tid];
            g1[0][tid] = fmaxf(x0 + bb, 0.f);
            g1[1][tid] = fmaxf(x1 + bb, 0.f);
            g1[2][tid] = fmaxf(x2 + bb, 0.f);
            g1[3][tid] = fmaxf(x3 + bb, 0.f);
        }
        __syncthreads();
        {
            float x0 = 0.f, x1 = 0.f, x2 = 0.f, x3 = 0.f;
            for (int k = 0; k < 256; k++) {
                float wv = fc2w[k * 256 + tid];
                x0 = fmaf(g1[0][k], wv, x0);
                x1 = fmaf(g1[1][k], wv, x1);
                x2 = fmaf(g1[2][k], wv, x2);
                x3 = fmaf(g1[3][k], wv, x3);
            }
            float bb = fc2b[tid];
            g2[0][tid] = fmaxf(x0 + bb, 0.f);
            g2[1][tid] = fmaxf(x1 + bb, 0.f);
            g2[2][tid] = fmaxf(x2 + bb, 0.f);
            g2[3][tid] = fmaxf(x3 + bb, 0.f);
        }
        __syncthreads();
        {
            int lane = tid & 63, wv = tid >> 6;
            float s = fmaf(g2[wv][lane], fc3w[lane],
                      fmaf(g2[wv][64 + lane], fc3w[64 + lane],
                      fmaf(g2[wv][128 + lane], fc3w[128 + lane],
                           g2[wv][192 + lane] * fc3w[192 + lane])));
            for (int off = 32; off > 0; off >>= 1) s += __shfl_down(s, off);
            if (lane == 0) out[gbase + wv] = s + fc3b[0];
        }
    }
}

extern "C" void kernel_launch(void* const* d_in, const int* in_sizes, int n_in,
                              void* d_out, int out_size, void* d_ws, size_t ws_size,
                              hipStream_t stream) {
    const float* x    = (const float*)d_in[0];
    const int*   ei   = (const int*)d_in[1];
    const int*   batch= (const int*)d_in[2];
    const float* W1   = (const float*)d_in[4];
    const float* b1   = (const float*)d_in[5];
    const float* W2   = (const float*)d_in[6];
    const float* b2   = (const float*)d_in[7];
    const float* bn1g = (const float*)d_in[8];
    const float* bn1b = (const float*)d_in[9];
    const float* bn2g = (const float*)d_in[10];
    const float* bn2b = (const float*)d_in[11];
    const float* fc1w = (const float*)d_in[12];
    const float* fc1b = (const float*)d_in[13];
    const float* fc2w = (const float*)d_in[14];
    const float* fc2b = (const float*)d_in[15];
    const float* fc3w = (const float*)d_in[16];
    const float* fc3b = (const float*)d_in[17];
    const int* src = ei;
    const int* dst = ei + NE;
    float* outp = (float*)d_out;

    char* w = (char*)d_ws;
    size_t o = 0;
    auto alloc = [&](size_t bytes) -> char* {
        char* p = w + o;
        o = (o + bytes + 255) & ~(size_t)255;
        return p;
    };
    int*   degT    = (int*)alloc((size_t)NCHUNK * NPAD * 4);   // written fully, no zeroing
    int*   baseT   = (int*)alloc((size_t)NCHUNK * NPAD * 4);
    int*   wsum    = (int*)alloc((size_t)NCHUNK * NWIN * 4);
    float* slots0  = (float*)alloc((size_t)2 * 64 * 256 * 4);  // zeroed in phase 1
    int*   row_ptr = (int*)alloc((size_t)(NN + 1) * 4);
    int*   rank    = (int*)alloc((size_t)NE * 4);
    u32*   col     = (u32*)alloc((size_t)NE * 4);
    float* dis     = (float*)alloc((size_t)NN * 4);
    unsigned short* wt2 = (unsigned short*)alloc(128 * 128 * 2);
    u32*   bufA    = (u32*)alloc((size_t)NN * 64 * 4);
    u32*   bufB    = (u32*)alloc((size_t)NN * 64 * 4);
    int*   bar     = (int*)alloc(256);

    hipMemsetAsync(bar, 0, 256, stream);
    k_mega<<<NB, 256, 0, stream>>>(x, src, dst, batch, W1, b1, W2, b2,
                                   bn1g, bn1b, bn2g, bn2b,
                                   fc1w, fc1b, fc2w, fc2b, fc3w, fc3b,
                                   degT, baseT, wsum, slots0, row_ptr, rank,
                                   col, dis, wt2, bufA, bufB, bar, outp);
}

// Round 5
// 287.861 us; speedup vs baseline: 4.8301x; 2.7576x over previous
//
#include <hip/hip_runtime.h>
#include <hip/hip_fp16.h>

#define NN 40000
#define NE 640000
#define DF 128
#define NG 2000
#define NCH 157        // ceil(NN/256) node windows (256-node)
#define CNTB 625       // count/fill blocks: NE/(256*4), 4 edges/thread
#define G1_BLKS 313    // ceil(NN/128) -- GEMM 128-row tiles
#define NDPAD 40192    // NCH*256 -- deg/curs padded length

typedef unsigned int u32;
typedef __attribute__((ext_vector_type(8))) short short8;
typedef __attribute__((ext_vector_type(4))) float floatx4;

// ---- bf16 helpers (packed u32: low 16 = even col, high = odd col) ----
__device__ inline float2 bf2_to_f2(u32 u) {
    return make_float2(__uint_as_float(u << 16), __uint_as_float(u & 0xffff0000u));
}
__device__ inline u32 f_to_bf(float f) {
    u32 u = __float_as_uint(f);
    return (u + 0x7fffu + ((u >> 16) & 1u)) >> 16;   // RNE
}
__device__ inline u32 pack_bf2(float a, float b) {
    return f_to_bf(a) | (f_to_bf(b) << 16);
}
__device__ inline float bf_to_f(short s) {
    return __uint_as_float(((u32)(unsigned short)s) << 16);
}
// packed col entry: low 16 = src index (<65536), high 16 = fp16(dis[src])
__device__ inline float colw_to_f(int cw) {
    return __half2float(__ushort_as_half((unsigned short)((u32)cw >> 16)));
}

// ---------------- MFMA GEMM core (LDS passed in: uni 34816B union, sc/sh 128 floats) ----------------
template<bool BF16IN, bool FUSE_BN, bool WT_F32, bool TILE128>
__device__ __forceinline__ void gemm_core(const void* __restrict__ Xv, const void* __restrict__ wsrc,
                                          u32* __restrict__ outb, const float* __restrict__ slots,
                                          const float* __restrict__ gam, const float* __restrict__ bet,
                                          int bid, char* sbuf, float* sc, float* sh) {
    unsigned short* wlds = (unsigned short*)sbuf;
    unsigned short* clds = (unsigned short*)sbuf;
    int tid = threadIdx.x;
    int row0 = bid * (TILE128 ? 128 : 64);

    if (FUSE_BN) {
        if (tid < 128) {
            float s = 0.f, q = 0.f;
            for (int k = 0; k < 64; k++) {
                s += slots[k * 256 + tid];
                q += slots[k * 256 + 128 + tid];
            }
            const float inv_n = 1.0f / (float)NN;
            float mu = s * inv_n;
            float va = fmaf(-mu, mu, q * inv_n);
            float a = gam[tid] * rsqrtf(va + 1e-5f);
            sc[tid] = a;
            sh[tid] = fmaf(-mu, a, bet[tid]);
        }
    }
    if (WT_F32) {
        const float* W = (const float*)wsrc;     // W[k][c] row-major fp32
        for (int i = tid; i < 16384; i += 256) {
            int k = i >> 7, c = i & 127;
            wlds[c * 136 + k] = (unsigned short)f_to_bf(W[i]);
        }
    } else {
        const unsigned short* wt = (const unsigned short*)wsrc;   // pre-transposed bf16
        for (int i = tid; i < 2048; i += 256) {
            int c = i >> 4, s = i & 15;
            *(uint4*)&wlds[c * 136 + s * 8] = ((const uint4*)wt)[i];
        }
    }
    __syncthreads();

    int lane = tid & 63;
    int wave = tid >> 6;
    int qr = lane >> 4;
    int rl = lane & 15;

    if (TILE128) {
        int rA0 = row0 + wave * 32 + rl;
        int rA1 = rA0 + 16;
        int rA0c = rA0 < NN ? rA0 : NN - 1;
        int rA1c = rA1 < NN ? rA1 : NN - 1;
        floatx4 acc[2][8];
#pragma unroll
        for (int a = 0; a < 2; a++)
#pragma unroll
            for (int b = 0; b < 8; b++) acc[a][b] = (floatx4){0.f, 0.f, 0.f, 0.f};
#pragma unroll
        for (int kb = 0; kb < 4; kb++) {
            int k0 = kb * 32 + qr * 8;
            short8 a0, a1;
            if (!BF16IN) {
                const float* p0 = (const float*)Xv + (size_t)rA0c * DF + k0;
                const float* p1 = (const float*)Xv + (size_t)rA1c * DF + k0;
                float4 u0 = *(const float4*)p0, u1 = *(const float4*)(p0 + 4);
                float4 v0 = *(const float4*)p1, v1 = *(const float4*)(p1 + 4);
                float fa[8] = {u0.x, u0.y, u0.z, u0.w, u1.x, u1.y, u1.z, u1.w};
                float fb[8] = {v0.x, v0.y, v0.z, v0.w, v1.x, v1.y, v1.z, v1.w};
#pragma unroll
                for (int j = 0; j < 8; j++) { a0[j] = (short)f_to_bf(fa[j]); a1[j] = (short)f_to_bf(fb[j]); }
            } else {
                a0 = *(const short8*)((const u32*)Xv + (size_t)rA0c * 64 + (k0 >> 1));
                a1 = *(const short8*)((const u32*)Xv + (size_t)rA1c * 64 + (k0 >> 1));
                if (FUSE_BN) {
#pragma unroll
                    for (int j = 0; j < 8; j++) {
                        float f0 = fmaxf(fmaf(bf_to_f(a0[j]), sc[k0 + j], sh[k0 + j]), 0.f);
                        float f1 = fmaxf(fmaf(bf_to_f(a1[j]), sc[k0 + j], sh[k0 + j]), 0.f);
                        a0[j] = (short)f_to_bf(f0);
                        a1[j] = (short)f_to_bf(f1);
                    }
                }
            }
#pragma unroll
            for (int ct = 0; ct < 8; ct++) {
                short8 bfr = *(const short8*)&wlds[(ct * 16 + rl) * 136 + k0];
                acc[0][ct] = __builtin_amdgcn_mfma_f32_16x16x32_bf16(a0, bfr, acc[0][ct], 0, 0, 0);
                acc[1][ct] = __builtin_amdgcn_mfma_f32_16x16x32_bf16(a1, bfr, acc[1][ct], 0, 0, 0);
            }
        }
        __syncthreads();
#pragma unroll
        for (int rt = 0; rt < 2; rt++)
#pragma unroll
            for (int ct = 0; ct < 8; ct++)
#pragma unroll
                for (int r = 0; r < 4; r++) {
                    int lr = wave * 32 + rt * 16 + qr * 4 + r;
                    int c = ct * 16 + rl;
                    clds[lr * 136 + c] = (unsigned short)f_to_bf(acc[rt][ct][r]);
                }
        __syncthreads();
        for (int i = tid; i < 2048; i += 256) {
            int lr = i >> 4, s = i & 15;
            int grow = row0 + lr;
            if (grow < NN) {
                uint4 v = *(const uint4*)&clds[lr * 136 + s * 8];
                ((uint4*)(outb + (size_t)grow * 64))[s] = v;
            }
        }
    } else {
        int rA = row0 + wave * 16 + rl;
        floatx4 acc[8];
#pragma unroll
        for (int b = 0; b < 8; b++) acc[b] = (floatx4){0.f, 0.f, 0.f, 0.f};
#pragma unroll
        for (int kb = 0; kb < 4; kb++) {
            int k0 = kb * 32 + qr * 8;
            short8 a0;
            if (!BF16IN) {
                const float* p0 = (const float*)Xv + (size_t)rA * DF + k0;
                float4 u0 = *(const float4*)p0, u1 = *(const float4*)(p0 + 4);
                float fa[8] = {u0.x, u0.y, u0.z, u0.w, u1.x, u1.y, u1.z, u1.w};
#pragma unroll
                for (int j = 0; j < 8; j++) a0[j] = (short)f_to_bf(fa[j]);
            } else {
                a0 = *(const short8*)((const u32*)Xv + (size_t)rA * 64 + (k0 >> 1));
                if (FUSE_BN) {
#pragma unroll
                    for (int j = 0; j < 8; j++) {
                        float f0 = fmaxf(fmaf(bf_to_f(a0[j]), sc[k0 + j], sh[k0 + j]), 0.f);
                        a0[j] = (short)f_to_bf(f0);
                    }
                }
            }
#pragma unroll
            for (int ct = 0; ct < 8; ct++) {
                short8 bfr = *(const short8*)&wlds[(ct * 16 + rl) * 136 + k0];
                acc[ct] = __builtin_amdgcn_mfma_f32_16x16x32_bf16(a0, bfr, acc[ct], 0, 0, 0);
            }
        }
        __syncthreads();
#pragma unroll
        for (int ct = 0; ct < 8; ct++)
#pragma unroll
            for (int r = 0; r < 4; r++) {
                int lr = wave * 16 + qr * 4 + r;
                int c = ct * 16 + rl;
                clds[lr * 136 + c] = (unsigned short)f_to_bf(acc[ct][r]);
            }
        __syncthreads();
        for (int i = tid; i < 1024; i += 256) {
            int lr = i >> 4, s = i & 15;
            uint4 v = *(const uint4*)&clds[lr * 136 + s * 8];
            ((uint4*)(outb + (size_t)(row0 + lr) * 64))[s] = v;
        }
    }
}

// ---------------- D1: degree count (global atomics) + slots zero + wt2 + GEMM1 ----------------
// deg[] pre-zeroed by hipMemsetAsync. Count replaces the old LDS-histogram machinery:
// 640k fire-and-forget atomicAdds spread over 40k L2-resident addresses.
__global__ __launch_bounds__(256, 4) void k_countgemm(const int* __restrict__ dst,
                                                      int* __restrict__ deg, float* __restrict__ slots0,
                                                      const float* __restrict__ W1, const float* __restrict__ W2,
                                                      unsigned short* __restrict__ wt2,
                                                      const float* __restrict__ X, u32* __restrict__ outb) {
    __shared__ __align__(16) char sbuf[34816];
    __shared__ float sc[128], sh[128];
    int bid = blockIdx.x;
    int tid = threadIdx.x;
    if (bid < CNTB) {
        int i4 = bid * 256 + tid;      // < 160000
        int4 d4 = ((const int4*)dst)[i4];
        atomicAdd(&deg[d4.x], 1);
        atomicAdd(&deg[d4.y], 1);
        atomicAdd(&deg[d4.z], 1);
        atomicAdd(&deg[d4.w], 1);
        return;
    }
    if (bid < CNTB + 2) {              // zero slotsA|slotsB
        float* s = slots0 + (size_t)(bid - CNTB) * 64 * 256;
        for (int i = tid; i < 64 * 256; i += 256) s[i] = 0.f;
        return;
    }
    if (bid == CNTB + 2) {             // wt2 transpose (consumed by k_gemm2)
        for (int i = tid; i < 128 * 128; i += 256) {
            int k = i >> 7, cc = i & 127;
            wt2[cc * 128 + k] = (unsigned short)f_to_bf(W2[i]);
        }
        return;
    }
    gemm_core<false, false, true, true>(X, W1, outb, nullptr, nullptr, nullptr,
                                        bid - CNTB - 3, sbuf, sc, sh);
}

// ---------------- D2: scan directly over deg -> row_ptr, curs, dis ----------------
__global__ __launch_bounds__(256) void k_scan(const int* __restrict__ deg,
                                              int* __restrict__ row_ptr, int* __restrict__ curs,
                                              float* __restrict__ dis) {
    __shared__ int red[256];
    __shared__ int ls[256];
    int tid = threadIdx.x;
    int wnd = blockIdx.x;
    // cross-window base: sum deg[0 .. wnd*256) (L2-hot, 157 blocks read broadcast-friendly)
    int part = 0;
    int lim = wnd * 256;
    for (int idx = tid; idx < lim; idx += 256) part += deg[idx];
    red[tid] = part;
    int n = lim + tid;                 // < NDPAD, deg zero-padded past NN
    int d = deg[n];
    ls[tid] = d;
    __syncthreads();
#pragma unroll
    for (int off = 128; off > 0; off >>= 1) {
        if (tid < off) red[tid] += red[tid + off];
        __syncthreads();
    }
    int base = red[0];
#pragma unroll
    for (int off = 1; off < 256; off <<= 1) {
        int t = (tid >= off) ? ls[tid - off] : 0;
        __syncthreads();
        ls[tid] += t;
        __syncthreads();
    }
    if (n < NN) {
        int r = base + ls[tid] - d;    // global exclusive prefix
        row_ptr[n] = r;
        curs[n] = r;
        dis[n] = rsqrtf((float)(d + 1));
    }
    if (wnd == NCH - 1 && tid == 0) row_ptr[NN] = NE;
}

// ---------------- D3: CSR fill via cursor atomics (no rank/baseT; order within row arbitrary) ----------------
__global__ __launch_bounds__(256) void k_fill(const int* __restrict__ src, const int* __restrict__ dst,
                                              int* __restrict__ curs,
                                              const float* __restrict__ dis, u32* __restrict__ col) {
    int i4 = blockIdx.x * 256 + threadIdx.x;   // < 160000
    int4 d4 = ((const int4*)dst)[i4];
    int4 s4 = ((const int4*)src)[i4];
    int dd[4] = {d4.x, d4.y, d4.z, d4.w};
    int ss[4] = {s4.x, s4.y, s4.z, s4.w};
#pragma unroll
    for (int q = 0; q < 4; q++) {
        u32 h = (u32)__half_as_ushort(__float2half(dis[ss[q]]));
        int slot = atomicAdd(&curs[dd[q]], 1);
        col[slot] = (u32)ss[q] | (h << 16);
    }
}

__global__ __launch_bounds__(256, 4) void k_gemm2(const u32* __restrict__ Hb, const unsigned short* __restrict__ wt2,
                                                  u32* __restrict__ outb, const float* __restrict__ slots,
                                                  const float* __restrict__ gam, const float* __restrict__ bet) {
    __shared__ __align__(16) char sbuf[34816];
    __shared__ float sc[128], sh[128];
    gemm_core<true, true, false, true>(Hb, wt2, outb, slots, gam, bet, blockIdx.x, sbuf, sc, sh);
}

// ---------------- GCN aggregation: one wave/node, 4 nodes/block; BN-stats fused ----------------
__global__ __launch_bounds__(256, 8) void k_gather(const u32* __restrict__ Hb, const int* __restrict__ row_ptr,
                                                   const u32* __restrict__ col, const float* __restrict__ dis,
                                                   const float* __restrict__ bias, u32* __restrict__ outb,
                                                   float* __restrict__ slots) {
    __shared__ float sred[4][128];
    __shared__ float qred[4][128];
    int t = threadIdx.x & 63;                       // lane: cols 2t, 2t+1
    int wv = threadIdx.x >> 6;
    int node = blockIdx.x * 4 + wv;
    float di = dis[node];
    int lo = row_ptr[node], hi = row_ptr[node + 1];
    float2 acc;
    {
        float2 a = bf2_to_f2(Hb[(size_t)node * 64 + t]);
        acc = make_float2(a.x * di, a.y * di);   // di factored: final acc *= di
    }
    for (int base = lo; base < hi; base += 64) {
        int m = hi - base; if (m > 64) m = 64;
        int cw = 0;
        if (t < m) cw = (int)col[base + t];
        int ng = (m + 3) >> 2;
        int c[4]; u32 u[4];
#pragma unroll
        for (int q = 0; q < 4; q++) {
            int idx = q < m ? q : 0;
            c[q] = __shfl(cw, idx);
            u[q] = Hb[(size_t)(c[q] & 0xffff) * 64 + t];
        }
        for (int g = 1; g < ng; g++) {
            int c2[4]; u32 u2[4];
#pragma unroll
            for (int q = 0; q < 4; q++) {
                int ii = g * 4 + q;
                int idx = ii < m ? ii : 0;
                c2[q] = __shfl(cw, idx);
                u2[q] = Hb[(size_t)(c2[q] & 0xffff) * 64 + t];
            }
#pragma unroll
            for (int q = 0; q < 4; q++) {
                int ii = (g - 1) * 4 + q;
                float wq = ii < m ? colw_to_f(c[q]) : 0.f;
                float2 h = bf2_to_f2(u[q]);
                acc.x = fmaf(h.x, wq, acc.x);
                acc.y = fmaf(h.y, wq, acc.y);
            }
#pragma unroll
            for (int q = 0; q < 4; q++) { c[q] = c2[q]; u[q] = u2[q]; }
        }
#pragma unroll
        for (int q = 0; q < 4; q++) {
            int ii = (ng - 1) * 4 + q;
            float wq = ii < m ? colw_to_f(c[q]) : 0.f;
            float2 h = bf2_to_f2(u[q]);
            acc.x = fmaf(h.x, wq, acc.x);
            acc.y = fmaf(h.y, wq, acc.y);
        }
    }
    float2 b = ((const float2*)bias)[t];
    acc.x = fmaf(acc.x, di, b.x);
    acc.y = fmaf(acc.y, di, b.y);
    outb[(size_t)node * 64 + t] = pack_bf2(acc.x, acc.y);
    // BN stats (pre-BN activations, incl. bias): block reduce -> 64-slot atomics
    sred[wv][2 * t] = acc.x;     sred[wv][2 * t + 1] = acc.y;
    qred[wv][2 * t] = acc.x * acc.x; qred[wv][2 * t + 1] = acc.y * acc.y;
    __syncthreads();
    int tid = threadIdx.x;
    if (tid < 128) {
        float s = sred[0][tid] + sred[1][tid] + sred[2][tid] + sred[3][tid];
        float q = qred[0][tid] + qred[1][tid] + qred[2][tid] + qred[3][tid];
        int slot = blockIdx.x & 63;
        atomicAdd(&slots[slot * 256 + tid], s);
        atomicAdd(&slots[slot * 256 + 128 + tid], q);
    }
}

// ---------------- pool (BN2+ReLU) + fc1 + fc2 + fc3, 4 graphs per block ----------------
__global__ __launch_bounds__(256) void k_poolfc(const u32* __restrict__ Hb, const int* __restrict__ batch,
                                                const float* __restrict__ slots,
                                                const float* __restrict__ gam, const float* __restrict__ bet,
                                                const float* __restrict__ fc1w, const float* __restrict__ fc1b,
                                                const float* __restrict__ fc2w, const float* __restrict__ fc2b,
                                                const float* __restrict__ fc3w, const float* __restrict__ fc3b,
                                                float* __restrict__ out) {
    __shared__ float sc[128], sh[128];
    __shared__ float pooled[4][128];
    __shared__ float g1[4][256];
    __shared__ float g2[4][256];
    __shared__ int bnds[5];
    int tid = threadIdx.x;
    int gbase = blockIdx.x * 4;
    if (tid < 128) {
        float s = 0.f, q = 0.f;
        for (int k = 0; k < 64; k++) {
            s += slots[k * 256 + tid];
            q += slots[k * 256 + 128 + tid];
        }
        const float inv_n = 1.0f / (float)NN;
        float mu = s * inv_n;
        float va = fmaf(-mu, mu, q * inv_n);
        float a = gam[tid] * rsqrtf(va + 1e-5f);
        sc[tid] = a;
        sh[tid] = fmaf(-mu, a, bet[tid]);
    } else if (tid < 133) {
        int target = gbase + (tid - 128);
        int a = 0, b = NN;
        while (a < b) { int m = (a + b) >> 1; if (batch[m] < target) a = m + 1; else b = m; }
        bnds[tid - 128] = a;
    }
    __syncthreads();
    {
        int g = tid >> 6, p = tid & 63;
        int lo = bnds[g], hi = bnds[g + 1];
        float a0 = 0.f, a1 = 0.f;
        float sc0 = sc[2 * p], sh0 = sh[2 * p], sc1 = sc[2 * p + 1], sh1 = sh[2 * p + 1];
        for (int i = lo; i < hi; i++) {
            float2 v = bf2_to_f2(Hb[(size_t)i * 64 + p]);
            a0 += fmaxf(fmaf(v.x, sc0, sh0), 0.f);
            a1 += fmaxf(fmaf(v.y, sc1, sh1), 0.f);
        }
        pooled[g][2 * p] = a0;
        pooled[g][2 * p + 1] = a1;
    }
    __syncthreads();
    {
        float x0 = 0.f, x1 = 0.f, x2 = 0.f, x3 = 0.f;
        for (int k = 0; k < 128; k++) {
            float wv = fc1w[k * 256 + tid];
            x0 = fmaf(pooled[0][k], wv, x0);
            x1 = fmaf(pooled[1][k], wv, x1);
            x2 = fmaf(pooled[2][k], wv, x2);
            x3 = fmaf(pooled[3][k], wv, x3);
        }
        float bb = fc1b[tid];
        g1[0][tid] = fmaxf(x0 + bb, 0.f);
        g1[1][tid] = fmaxf(x1 + bb, 0.f);
        g1[2][tid] = fmaxf(x2 + bb, 0.f);
        g1[3][tid] = fmaxf(x3 + bb, 0.f);
    }
    __syncthreads();
    {
        float x0 = 0.f, x1 = 0.f, x2 = 0.f, x3 = 0.f;
        for (int k = 0; k < 256; k++) {
            float wv = fc2w[k * 256 + tid];
            x0 = fmaf(g1[0][k], wv, x0);
            x1 = fmaf(g1[1][k], wv, x1);
            x2 = fmaf(g1[2][k], wv, x2);
            x3 = fmaf(g1[3][k], wv, x3);
        }
        float bb = fc2b[tid];
        g2[0][tid] = fmaxf(x0 + bb, 0.f);
        g2[1][tid] = fmaxf(x1 + bb, 0.f);
        g2[2][tid] = fmaxf(x2 + bb, 0.f);
        g2[3][tid] = fmaxf(x3 + bb, 0.f);
    }
    __syncthreads();
    {
        int lane = tid & 63, wv = tid >> 6;
        float s = fmaf(g2[wv][lane], fc3w[lane],
                  fmaf(g2[wv][64 + lane], fc3w[64 + lane],
                  fmaf(g2[wv][128 + lane], fc3w[128 + lane],
                       g2[wv][192 + lane] * fc3w[192 + lane])));
        for (int off = 32; off > 0; off >>= 1) s += __shfl_down(s, off);
        if (lane == 0) out[gbase + wv] = s + fc3b[0];
    }
}

extern "C" void kernel_launch(void* const* d_in, const int* in_sizes, int n_in,
                              void* d_out, int out_size, void* d_ws, size_t ws_size,
                              hipStream_t stream) {
    const float* x    = (const float*)d_in[0];
    const int*   ei   = (const int*)d_in[1];
    const int*   batch= (const int*)d_in[2];
    const float* W1   = (const float*)d_in[4];
    const float* b1   = (const float*)d_in[5];
    const float* W2   = (const float*)d_in[6];
    const float* b2   = (const float*)d_in[7];
    const float* bn1g = (const float*)d_in[8];
    const float* bn1b = (const float*)d_in[9];
    const float* bn2g = (const float*)d_in[10];
    const float* bn2b = (const float*)d_in[11];
    const float* fc1w = (const float*)d_in[12];
    const float* fc1b = (const float*)d_in[13];
    const float* fc2w = (const float*)d_in[14];
    const float* fc2b = (const float*)d_in[15];
    const float* fc3w = (const float*)d_in[16];
    const float* fc3b = (const float*)d_in[17];
    const int* src = ei;
    const int* dst = ei + NE;
    float* outp = (float*)d_out;

    char* w = (char*)d_ws;
    size_t o = 0;
    auto alloc = [&](size_t bytes) -> char* {
        char* p = w + o;
        o = (o + bytes + 255) & ~(size_t)255;
        return p;
    };
    int*   deg     = (int*)alloc((size_t)NDPAD * 4);           // zeroed via memset below
    int*   curs    = (int*)alloc((size_t)NDPAD * 4);           // init by k_scan
    float* slots0  = (float*)alloc((size_t)2 * 64 * 256 * 4);  // zeroed in count dispatch
    int*   row_ptr = (int*)alloc((size_t)(NN + 1) * 4);
    u32*   col     = (u32*)alloc((size_t)NE * 4);
    float* dis     = (float*)alloc((size_t)NN * 4);
    unsigned short* wt2 = (unsigned short*)alloc(128 * 128 * 2);
    u32*   bufA    = (u32*)alloc((size_t)NN * 64 * 4);
    u32*   bufB    = (u32*)alloc((size_t)NN * 64 * 4);
    float* slotsA  = slots0;
    float* slotsB  = slots0 + 64 * 256;

    hipMemsetAsync(deg, 0, (size_t)NDPAD * 4, stream);
    k_countgemm<<<CNTB + 3 + G1_BLKS, 256, 0, stream>>>(dst, deg, slots0, W1, W2, wt2, x, bufA);
    k_scan<<<NCH, 256, 0, stream>>>(deg, row_ptr, curs, dis);
    k_fill<<<CNTB, 256, 0, stream>>>(src, dst, curs, dis, col);
    k_gather<<<NN / 4, 256, 0, stream>>>(bufA, row_ptr, col, dis, b1, bufB, slotsA);
    k_gemm2<<<G1_BLKS, 256, 0, stream>>>(bufB, wt2, bufA, slotsA, bn1g, bn1b);
    k_gather<<<NN / 4, 256, 0, stream>>>(bufA, row_ptr, col, dis, b2, bufB, slotsB);
    k_poolfc<<<NG / 4, 256, 0, stream>>>(bufB, batch, slotsB, bn2g, bn2b,
                                         fc1w, fc1b, fc2w, fc2b, fc3w, fc3b, outp);
}

// Round 6
// 280.194 us; speedup vs baseline: 4.9622x; 1.0274x over previous
//
#include <hip/hip_runtime.h>
#include <hip/hip_fp16.h>

#define NN 40000
#define NE 640000
#define DF 128
#define NG 2000
#define NCH 157        // ceil(NN/256) node windows (256-node)
#define CNTB 625       // count/fill blocks: NE/(256*4), 4 edges/thread
#define GT_BLKS 625    // NN/64 -- 64-row GEMM tiles (2.4 blocks/CU spread)
#define NDPAD 40192    // NCH*256 -- deg/curs padded length

typedef unsigned int u32;
typedef __attribute__((ext_vector_type(8))) short short8;
typedef __attribute__((ext_vector_type(4))) float floatx4;

// ---- bf16 helpers (packed u32: low 16 = even col, high = odd col) ----
__device__ inline float2 bf2_to_f2(u32 u) {
    return make_float2(__uint_as_float(u << 16), __uint_as_float(u & 0xffff0000u));
}
__device__ inline u32 f_to_bf(float f) {
    u32 u = __float_as_uint(f);
    return (u + 0x7fffu + ((u >> 16) & 1u)) >> 16;   // RNE
}
__device__ inline u32 pack_bf2(float a, float b) {
    return f_to_bf(a) | (f_to_bf(b) << 16);
}
__device__ inline float bf_to_f(short s) {
    return __uint_as_float(((u32)(unsigned short)s) << 16);
}
// packed col entry: low 16 = src index (<65536), high 16 = fp16(dis[src])
__device__ inline float colw_to_f(int cw) {
    return __half2float(__ushort_as_half((unsigned short)((u32)cw >> 16)));
}

// ---------------- MFMA GEMM core, 64-row tile ----------------
// LDS union sbuf = 32768 B: wlds = W^T bf16 [128 rows c][128 k], XOR-swizzled
// (chunk ^= row&7, chunk = 16B/8-elem unit) -> stride 128, conflict-free, 32KB exact.
// clds (C staging) uses the same swizzle. sc/sh only referenced when FUSE_BN.
template<bool BF16IN, bool FUSE_BN>
__device__ __forceinline__ void gemm_core(const void* __restrict__ Xv, const unsigned short* __restrict__ wt,
                                          u32* __restrict__ outb, const float* __restrict__ slots,
                                          const float* __restrict__ gam, const float* __restrict__ bet,
                                          int bid, char* sbuf, float* sc, float* sh) {
    unsigned short* wlds = (unsigned short*)sbuf;
    unsigned short* clds = (unsigned short*)sbuf;
    int tid = threadIdx.x;
    int row0 = bid * 64;

    if (FUSE_BN) {
        if (tid < 128) {
            float s = 0.f, q = 0.f;
            for (int k = 0; k < 64; k++) {
                s += slots[k * 256 + tid];
                q += slots[k * 256 + 128 + tid];
            }
            const float inv_n = 1.0f / (float)NN;
            float mu = s * inv_n;
            float va = fmaf(-mu, mu, q * inv_n);
            float a = gam[tid] * rsqrtf(va + 1e-5f);
            sc[tid] = a;
            sh[tid] = fmaf(-mu, a, bet[tid]);
        }
    }
    // stage W^T (pre-transposed bf16) into swizzled LDS: 8 uint4 per thread
    for (int i = tid; i < 2048; i += 256) {
        int c = i >> 4, s = i & 15;
        *(uint4*)&wlds[c * 128 + ((s ^ (c & 7)) << 3)] = ((const uint4*)wt)[i];
    }
    __syncthreads();

    int lane = tid & 63;
    int wave = tid >> 6;
    int qr = lane >> 4;
    int rl = lane & 15;

    int rA = row0 + wave * 16 + rl;   // < NN always (625*64 == NN)
    floatx4 acc[8];
#pragma unroll
    for (int b = 0; b < 8; b++) acc[b] = (floatx4){0.f, 0.f, 0.f, 0.f};
#pragma unroll
    for (int kb = 0; kb < 4; kb++) {
        int k0 = kb * 32 + qr * 8;
        short8 a0;
        if (!BF16IN) {
            const float* p0 = (const float*)Xv + (size_t)rA * DF + k0;
            float4 u0 = *(const float4*)p0, u1 = *(const float4*)(p0 + 4);
            float fa[8] = {u0.x, u0.y, u0.z, u0.w, u1.x, u1.y, u1.z, u1.w};
#pragma unroll
            for (int j = 0; j < 8; j++) a0[j] = (short)f_to_bf(fa[j]);
        } else {
            a0 = *(const short8*)((const u32*)Xv + (size_t)rA * 64 + (k0 >> 1));
            if (FUSE_BN) {
#pragma unroll
                for (int j = 0; j < 8; j++) {
                    float f0 = fmaxf(fmaf(bf_to_f(a0[j]), sc[k0 + j], sh[k0 + j]), 0.f);
                    a0[j] = (short)f_to_bf(f0);
                }
            }
        }
#pragma unroll
        for (int ct = 0; ct < 8; ct++) {
            int rowB = ct * 16 + rl;   // rowB&7 == rl&7
            short8 bfr = *(const short8*)&wlds[rowB * 128 + ((((kb << 2) + qr) ^ (rl & 7)) << 3)];
            acc[ct] = __builtin_amdgcn_mfma_f32_16x16x32_bf16(a0, bfr, acc[ct], 0, 0, 0);
        }
    }
    __syncthreads();
#pragma unroll
    for (int ct = 0; ct < 8; ct++)
#pragma unroll
        for (int r = 0; r < 4; r++) {
            int lr = wave * 16 + qr * 4 + r;
            int c = ct * 16 + rl;
            clds[lr * 128 + (((c >> 3) ^ (lr & 7)) << 3) + (c & 7)] = (unsigned short)f_to_bf(acc[ct][r]);
        }
    __syncthreads();
    for (int i = tid; i < 1024; i += 256) {
        int lr = i >> 4, s = i & 15;
        uint4 v = *(const uint4*)&clds[lr * 128 + ((s ^ (lr & 7)) << 3)];
        ((uint4*)(outb + (size_t)(row0 + lr) * 64))[s] = v;
    }
}

// ---------------- D0: prep -- wt1/wt2 transpose (bf16), zero slots + deg ----------------
__global__ __launch_bounds__(256) void k_prep(const float* __restrict__ W1, const float* __restrict__ W2,
                                              unsigned short* __restrict__ wt1, unsigned short* __restrict__ wt2,
                                              float* __restrict__ slots0, int* __restrict__ deg) {
    int bid = blockIdx.x, tid = threadIdx.x;
    if (bid < 64) {                     // slots0: 2*64*256 = 32768 floats
        slots0[bid * 512 + tid] = 0.f;
        slots0[bid * 512 + 256 + tid] = 0.f;
    } else if (bid < 104) {             // deg: NDPAD ints, 40 blocks x 1024
        int i = (bid - 64) * 1024 + tid;
#pragma unroll
        for (int q = 0; q < 4; q++) {
            int j = i + q * 256;
            if (j < NDPAD) deg[j] = 0;
        }
    } else if (bid < 168) {             // wt1[c*128+k] = bf16(W1[k][c]); coalesced writes
        int i = (bid - 104) * 256 + tid;
        wt1[i] = (unsigned short)f_to_bf(W1[(i & 127) * 128 + (i >> 7)]);
    } else {                            // wt2 same (64 blocks)
        int i = (bid - 168) * 256 + tid;
        wt2[i] = (unsigned short)f_to_bf(W2[(i & 127) * 128 + (i >> 7)]);
    }
}

// ---------------- D1: degree count (global atomics) + GEMM1 (1250 blocks, 5/CU capable) ----------------
__global__ __launch_bounds__(256, 5) void k_countgemm(const int* __restrict__ dst,
                                                      int* __restrict__ deg,
                                                      const unsigned short* __restrict__ wt1,
                                                      const float* __restrict__ X, u32* __restrict__ outb) {
    __shared__ __align__(16) char sbuf[32768];
    int bid = blockIdx.x;
    int tid = threadIdx.x;
    if (bid < CNTB) {
        int i4 = bid * 256 + tid;      // < 160000
        int4 d4 = ((const int4*)dst)[i4];
        atomicAdd(&deg[d4.x], 1);
        atomicAdd(&deg[d4.y], 1);
        atomicAdd(&deg[d4.z], 1);
        atomicAdd(&deg[d4.w], 1);
        return;
    }
    gemm_core<false, false>(X, wt1, outb, nullptr, nullptr, nullptr,
                            bid - CNTB, sbuf, nullptr, nullptr);
}

// ---------------- D2: scan directly over deg -> row_ptr, curs, dis ----------------
__global__ __launch_bounds__(256) void k_scan(const int* __restrict__ deg,
                                              int* __restrict__ row_ptr, int* __restrict__ curs,
                                              float* __restrict__ dis) {
    __shared__ int red[256];
    __shared__ int ls[256];
    int tid = threadIdx.x;
    int wnd = blockIdx.x;
    int part = 0;
    int lim = wnd * 256;
    for (int idx = tid; idx < lim; idx += 256) part += deg[idx];
    red[tid] = part;
    int n = lim + tid;                 // < NDPAD, deg zero-padded past NN
    int d = deg[n];
    ls[tid] = d;
    __syncthreads();
#pragma unroll
    for (int off = 128; off > 0; off >>= 1) {
        if (tid < off) red[tid] += red[tid + off];
        __syncthreads();
    }
    int base = red[0];
#pragma unroll
    for (int off = 1; off < 256; off <<= 1) {
        int t = (tid >= off) ? ls[tid - off] : 0;
        __syncthreads();
        ls[tid] += t;
        __syncthreads();
    }
    if (n < NN) {
        int r = base + ls[tid] - d;    // global exclusive prefix
        row_ptr[n] = r;
        curs[n] = r;
        dis[n] = rsqrtf((float)(d + 1));
    }
    if (wnd == NCH - 1 && tid == 0) row_ptr[NN] = NE;
}

// ---------------- D3: CSR fill via cursor atomics ----------------
__global__ __launch_bounds__(256) void k_fill(const int* __restrict__ src, const int* __restrict__ dst,
                                              int* __restrict__ curs,
                                              const float* __restrict__ dis, u32* __restrict__ col) {
    int i4 = blockIdx.x * 256 + threadIdx.x;   // < 160000
    int4 d4 = ((const int4*)dst)[i4];
    int4 s4 = ((const int4*)src)[i4];
    int dd[4] = {d4.x, d4.y, d4.z, d4.w};
    int ss[4] = {s4.x, s4.y, s4.z, s4.w};
#pragma unroll
    for (int q = 0; q < 4; q++) {
        u32 h = (u32)__half_as_ushort(__float2half(dis[ss[q]]));
        int slot = atomicAdd(&curs[dd[q]], 1);
        col[slot] = (u32)ss[q] | (h << 16);
    }
}

__global__ __launch_bounds__(256, 4) void k_gemm2(const u32* __restrict__ Hb, const unsigned short* __restrict__ wt2,
                                                  u32* __restrict__ outb, const float* __restrict__ slots,
                                                  const float* __restrict__ gam, const float* __restrict__ bet) {
    __shared__ __align__(16) char sbuf[32768];
    __shared__ float sc[128], sh[128];
    gemm_core<true, true>(Hb, wt2, outb, slots, gam, bet, blockIdx.x, sbuf, sc, sh);
}

// ---------------- GCN aggregation: one wave/node, 4 nodes/block; BN-stats fused ----------------
__global__ __launch_bounds__(256, 8) void k_gather(const u32* __restrict__ Hb, const int* __restrict__ row_ptr,
                                                   const u32* __restrict__ col, const float* __restrict__ dis,
                                                   const float* __restrict__ bias, u32* __restrict__ outb,
                                                   float* __restrict__ slots) {
    __shared__ float sred[4][128];
    __shared__ float qred[4][128];
    int t = threadIdx.x & 63;                       // lane: cols 2t, 2t+1
    int wv = threadIdx.x >> 6;
    int node = blockIdx.x * 4 + wv;
    float di = dis[node];
    int lo = row_ptr[node], hi = row_ptr[node + 1];
    float2 acc;
    {
        float2 a = bf2_to_f2(Hb[(size_t)node * 64 + t]);
        acc = make_float2(a.x * di, a.y * di);   // di factored: final acc *= di
    }
    for (int base = lo; base < hi; base += 64) {
        int m = hi - base; if (m > 64) m = 64;
        int cw = 0;
        if (t < m) cw = (int)col[base + t];
        int ng = (m + 3) >> 2;
        int c[4]; u32 u[4];
#pragma unroll
        for (int q = 0; q < 4; q++) {
            int idx = q < m ? q : 0;
            c[q] = __shfl(cw, idx);
            u[q] = Hb[(size_t)(c[q] & 0xffff) * 64 + t];
        }
        for (int g = 1; g < ng; g++) {
            int c2[4]; u32 u2[4];
#pragma unroll
            for (int q = 0; q < 4; q++) {
                int ii = g * 4 + q;
                int idx = ii < m ? ii : 0;
                c2[q] = __shfl(cw, idx);
                u2[q] = Hb[(size_t)(c2[q] & 0xffff) * 64 + t];
            }
#pragma unroll
            for (int q = 0; q < 4; q++) {
                int ii = (g - 1) * 4 + q;
                float wq = ii < m ? colw_to_f(c[q]) : 0.f;
                float2 h = bf2_to_f2(u[q]);
                acc.x = fmaf(h.x, wq, acc.x);
                acc.y = fmaf(h.y, wq, acc.y);
            }
#pragma unroll
            for (int q = 0; q < 4; q++) { c[q] = c2[q]; u[q] = u2[q]; }
        }
#pragma unroll
        for (int q = 0; q < 4; q++) {
            int ii = (ng - 1) * 4 + q;
            float wq = ii < m ? colw_to_f(c[q]) : 0.f;
            float2 h = bf2_to_f2(u[q]);
            acc.x = fmaf(h.x, wq, acc.x);
            acc.y = fmaf(h.y, wq, acc.y);
        }
    }
    float2 b = ((const float2*)bias)[t];
    acc.x = fmaf(acc.x, di, b.x);
    acc.y = fmaf(acc.y, di, b.y);
    outb[(size_t)node * 64 + t] = pack_bf2(acc.x, acc.y);
    // BN stats (pre-BN activations, incl. bias): block reduce -> 64-slot atomics
    sred[wv][2 * t] = acc.x;     sred[wv][2 * t + 1] = acc.y;
    qred[wv][2 * t] = acc.x * acc.x; qred[wv][2 * t + 1] = acc.y * acc.y;
    __syncthreads();
    int tid = threadIdx.x;
    if (tid < 128) {
        float s = sred[0][tid] + sred[1][tid] + sred[2][tid] + sred[3][tid];
        float q = qred[0][tid] + qred[1][tid] + qred[2][tid] + qred[3][tid];
        int slot = blockIdx.x & 63;
        atomicAdd(&slots[slot * 256 + tid], s);
        atomicAdd(&slots[slot * 256 + 128 + tid], q);
    }
}

// ---------------- pool (BN2+ReLU) + fc1 + fc2 + fc3, 4 graphs per block ----------------
__global__ __launch_bounds__(256) void k_poolfc(const u32* __restrict__ Hb, const int* __restrict__ batch,
                                                const float* __restrict__ slots,
                                                const float* __restrict__ gam, const float* __restrict__ bet,
                                                const float* __restrict__ fc1w, const float* __restrict__ fc1b,
                                                const float* __restrict__ fc2w, const float* __restrict__ fc2b,
                                                const float* __restrict__ fc3w, const float* __restrict__ fc3b,
                                                float* __restrict__ out) {
    __shared__ float sc[128], sh[128];
    __shared__ float pooled[4][128];
    __shared__ float g1[4][256];
    __shared__ float g2[4][256];
    __shared__ int bnds[5];
    int tid = threadIdx.x;
    int gbase = blockIdx.x * 4;
    if (tid < 128) {
        float s = 0.f, q = 0.f;
        for (int k = 0; k < 64; k++) {
            s += slots[k * 256 + tid];
            q += slots[k * 256 + 128 + tid];
        }
        const float inv_n = 1.0f / (float)NN;
        float mu = s * inv_n;
        float va = fmaf(-mu, mu, q * inv_n);
        float a = gam[tid] * rsqrtf(va + 1e-5f);
        sc[tid] = a;
        sh[tid] = fmaf(-mu, a, bet[tid]);
    } else if (tid < 133) {
        int target = gbase + (tid - 128);
        int a = 0, b = NN;
        while (a < b) { int m = (a + b) >> 1; if (batch[m] < target) a = m + 1; else b = m; }
        bnds[tid - 128] = a;
    }
    __syncthreads();
    {
        int g = tid >> 6, p = tid & 63;
        int lo = bnds[g], hi = bnds[g + 1];
        float a0 = 0.f, a1 = 0.f;
        float sc0 = sc[2 * p], sh0 = sh[2 * p], sc1 = sc[2 * p + 1], sh1 = sh[2 * p + 1];
        for (int i = lo; i < hi; i++) {
            float2 v = bf2_to_f2(Hb[(size_t)i * 64 + p]);
            a0 += fmaxf(fmaf(v.x, sc0, sh0), 0.f);
            a1 += fmaxf(fmaf(v.y, sc1, sh1), 0.f);
        }
        pooled[g][2 * p] = a0;
        pooled[g][2 * p + 1] = a1;
    }
    __syncthreads();
    {
        float x0 = 0.f, x1 = 0.f, x2 = 0.f, x3 = 0.f;
        for (int k = 0; k < 128; k++) {
            float wv = fc1w[k * 256 + tid];
            x0 = fmaf(pooled[0][k], wv, x0);
            x1 = fmaf(pooled[1][k], wv, x1);
            x2 = fmaf(pooled[2][k], wv, x2);
            x3 = fmaf(pooled[3][k], wv, x3);
        }
        float bb = fc1b[tid];
        g1[0][tid] = fmaxf(x0 + bb, 0.f);
        g1[1][tid] = fmaxf(x1 + bb, 0.f);
        g1[2][tid] = fmaxf(x2 + bb, 0.f);
        g1[3][tid] = fmaxf(x3 + bb, 0.f);
    }
    __syncthreads();
    {
        float x0 = 0.f, x1 = 0.f, x2 = 0.f, x3 = 0.f;
        for (int k = 0; k < 256; k++) {
            float wv = fc2w[k * 256 + tid];
            x0 = fmaf(g1[0][k], wv, x0);
            x1 = fmaf(g1[1][k], wv, x1);
            x2 = fmaf(g1[2][k], wv, x2);
            x3 = fmaf(g1[3][k], wv, x3);
        }
        float bb = fc2b[tid];
        g2[0][tid] = fmaxf(x0 + bb, 0.f);
        g2[1][tid] = fmaxf(x1 + bb, 0.f);
        g2[2][tid] = fmaxf(x2 + bb, 0.f);
        g2[3][tid] = fmaxf(x3 + bb, 0.f);
    }
    __syncthreads();
    {
        int lane = tid & 63, wv = tid >> 6;
        float s = fmaf(g2[wv][lane], fc3w[lane],
                  fmaf(g2[wv][64 + lane], fc3w[64 + lane],
                  fmaf(g2[wv][128 + lane], fc3w[128 + lane],
                       g2[wv][192 + lane] * fc3w[192 + lane])));
        for (int off = 32; off > 0; off >>= 1) s += __shfl_down(s, off);
        if (lane == 0) out[gbase + wv] = s + fc3b[0];
    }
}

extern "C" void kernel_launch(void* const* d_in, const int* in_sizes, int n_in,
                              void* d_out, int out_size, void* d_ws, size_t ws_size,
                              hipStream_t stream) {
    const float* x    = (const float*)d_in[0];
    const int*   ei   = (const int*)d_in[1];
    const int*   batch= (const int*)d_in[2];
    const float* W1   = (const float*)d_in[4];
    const float* b1   = (const float*)d_in[5];
    const float* W2   = (const float*)d_in[6];
    const float* b2   = (const float*)d_in[7];
    const float* bn1g = (const float*)d_in[8];
    const float* bn1b = (const float*)d_in[9];
    const float* bn2g = (const float*)d_in[10];
    const float* bn2b = (const float*)d_in[11];
    const float* fc1w = (const float*)d_in[12];
    const float* fc1b = (const float*)d_in[13];
    const float* fc2w = (const float*)d_in[14];
    const float* fc2b = (const float*)d_in[15];
    const float* fc3w = (const float*)d_in[16];
    const float* fc3b = (const float*)d_in[17];
    const int* src = ei;
    const int* dst = ei + NE;
    float* outp = (float*)d_out;

    char* w = (char*)d_ws;
    size_t o = 0;
    auto alloc = [&](size_t bytes) -> char* {
        char* p = w + o;
        o = (o + bytes + 255) & ~(size_t)255;
        return p;
    };
    int*   deg     = (int*)alloc((size_t)NDPAD * 4);           // zeroed in k_prep
    int*   curs    = (int*)alloc((size_t)NDPAD * 4);           // init by k_scan
    float* slots0  = (float*)alloc((size_t)2 * 64 * 256 * 4);  // zeroed in k_prep
    int*   row_ptr = (int*)alloc((size_t)(NN + 1) * 4);
    u32*   col     = (u32*)alloc((size_t)NE * 4);
    float* dis     = (float*)alloc((size_t)NN * 4);
    unsigned short* wt1 = (unsigned short*)alloc(128 * 128 * 2);
    unsigned short* wt2 = (unsigned short*)alloc(128 * 128 * 2);
    u32*   bufA    = (u32*)alloc((size_t)NN * 64 * 4);
    u32*   bufB    = (u32*)alloc((size_t)NN * 64 * 4);
    float* slotsA  = slots0;
    float* slotsB  = slots0 + 64 * 256;

    k_prep<<<232, 256, 0, stream>>>(W1, W2, wt1, wt2, slots0, deg);
    k_countgemm<<<CNTB + GT_BLKS, 256, 0, stream>>>(dst, deg, wt1, x, bufA);
    k_scan<<<NCH, 256, 0, stream>>>(deg, row_ptr, curs, dis);
    k_fill<<<CNTB, 256, 0, stream>>>(src, dst, curs, dis, col);
    k_gather<<<NN / 4, 256, 0, stream>>>(bufA, row_ptr, col, dis, b1, bufB, slotsA);
    k_gemm2<<<GT_BLKS, 256, 0, stream>>>(bufB, wt2, bufA, slotsA, bn1g, bn1b);
    k_gather<<<NN / 4, 256, 0, stream>>>(bufA, row_ptr, col, dis, b2, bufB, slotsB);
    k_poolfc<<<NG / 4, 256, 0, stream>>>(bufB, batch, slotsB, bn2g, bn2b,
                                         fc1w, fc1b, fc2w, fc2b, fc3w, fc3b, outp);
}

// Round 7
// 247.188 us; speedup vs baseline: 5.6248x; 1.1335x over previous
//
#include <hip/hip_runtime.h>
#include <hip/hip_fp16.h>

#define NN 40000
#define NE 640000
#define DF 128
#define NG 2000
#define NCH 157        // ceil(NN/256) node windows (256-node)
#define FILLB 625      // NE / (256*4) edge blocks, 4 edges/thread
#define GT_BLKS 625    // NN/64 -- 64-row GEMM tiles
#define NCHUNK 64      // edge chunks
#define ECH 10000      // NE / NCHUNK
#define NOCT 8         // node eighths
#define QN 5120        // nodes per eighth (window-aligned: 20 windows of 256)
#define NPAD (NOCT * QN)   // 40960 padded nodes
#define NWIN 160       // NPAD / 256 windows
#define HISTB (NCHUNK * NOCT)  // 512 hist blocks

typedef unsigned int u32;
typedef __attribute__((ext_vector_type(8))) short short8;
typedef __attribute__((ext_vector_type(4))) float floatx4;

// ---- bf16 helpers (packed u32: low 16 = even col, high = odd col) ----
__device__ inline float2 bf2_to_f2(u32 u) {
    return make_float2(__uint_as_float(u << 16), __uint_as_float(u & 0xffff0000u));
}
__device__ inline u32 f_to_bf(float f) {
    u32 u = __float_as_uint(f);
    return (u + 0x7fffu + ((u >> 16) & 1u)) >> 16;   // RNE
}
__device__ inline u32 pack_bf2(float a, float b) {
    return f_to_bf(a) | (f_to_bf(b) << 16);
}
__device__ inline float bf_to_f(short s) {
    return __uint_as_float(((u32)(unsigned short)s) << 16);
}
// packed col entry: low 16 = src index (<65536), high 16 = fp16(dis[src])
__device__ inline float colw_to_f(int cw) {
    return __half2float(__ushort_as_half((unsigned short)((u32)cw >> 16)));
}

// ---------------- MFMA GEMM core, 64-row tile ----------------
// LDS sbuf = 32768 B: wlds = W^T bf16 [128 c][128 k], XOR-swizzled (16B chunk ^= row&7)
// -> stride 128, conflict-free. clds (C staging) same swizzle. Weights pre-transposed (k_prep).
template<bool BF16IN, bool FUSE_BN>
__device__ __forceinline__ void gemm_core(const void* __restrict__ Xv, const unsigned short* __restrict__ wt,
                                          u32* __restrict__ outb, const float* __restrict__ slots,
                                          const float* __restrict__ gam, const float* __restrict__ bet,
                                          int bid, char* sbuf, float* sc, float* sh) {
    unsigned short* wlds = (unsigned short*)sbuf;
    unsigned short* clds = (unsigned short*)sbuf;
    int tid = threadIdx.x;
    int row0 = bid * 64;

    if (FUSE_BN) {
        if (tid < 128) {
            float s = 0.f, q = 0.f;
            for (int k = 0; k < 64; k++) {
                s += slots[k * 256 + tid];
                q += slots[k * 256 + 128 + tid];
            }
            const float inv_n = 1.0f / (float)NN;
            float mu = s * inv_n;
            float va = fmaf(-mu, mu, q * inv_n);
            float a = gam[tid] * rsqrtf(va + 1e-5f);
            sc[tid] = a;
            sh[tid] = fmaf(-mu, a, bet[tid]);
        }
    }
    // stage W^T (pre-transposed bf16) into swizzled LDS: 8 uint4 per thread
    for (int i = tid; i < 2048; i += 256) {
        int c = i >> 4, s = i & 15;
        *(uint4*)&wlds[c * 128 + ((s ^ (c & 7)) << 3)] = ((const uint4*)wt)[i];
    }
    __syncthreads();

    int lane = tid & 63;
    int wave = tid >> 6;
    int qr = lane >> 4;
    int rl = lane & 15;

    int rA = row0 + wave * 16 + rl;   // < NN always (625*64 == NN)
    floatx4 acc[8];
#pragma unroll
    for (int b = 0; b < 8; b++) acc[b] = (floatx4){0.f, 0.f, 0.f, 0.f};
#pragma unroll
    for (int kb = 0; kb < 4; kb++) {
        int k0 = kb * 32 + qr * 8;
        short8 a0;
        if (!BF16IN) {
            const float* p0 = (const float*)Xv + (size_t)rA * DF + k0;
            float4 u0 = *(const float4*)p0, u1 = *(const float4*)(p0 + 4);
            float fa[8] = {u0.x, u0.y, u0.z, u0.w, u1.x, u1.y, u1.z, u1.w};
#pragma unroll
            for (int j = 0; j < 8; j++) a0[j] = (short)f_to_bf(fa[j]);
        } else {
            a0 = *(const short8*)((const u32*)Xv + (size_t)rA * 64 + (k0 >> 1));
            if (FUSE_BN) {
#pragma unroll
                for (int j = 0; j < 8; j++) {
                    float f0 = fmaxf(fmaf(bf_to_f(a0[j]), sc[k0 + j], sh[k0 + j]), 0.f);
                    a0[j] = (short)f_to_bf(f0);
                }
            }
        }
#pragma unroll
        for (int ct = 0; ct < 8; ct++) {
            int rowB = ct * 16 + rl;   // rowB&7 == rl&7
            short8 bfr = *(const short8*)&wlds[rowB * 128 + ((((kb << 2) + qr) ^ (rl & 7)) << 3)];
            acc[ct] = __builtin_amdgcn_mfma_f32_16x16x32_bf16(a0, bfr, acc[ct], 0, 0, 0);
        }
    }
    __syncthreads();
#pragma unroll
    for (int ct = 0; ct < 8; ct++)
#pragma unroll
        for (int r = 0; r < 4; r++) {
            int lr = wave * 16 + qr * 4 + r;
            int c = ct * 16 + rl;
            clds[lr * 128 + (((c >> 3) ^ (lr & 7)) << 3) + (c & 7)] = (unsigned short)f_to_bf(acc[ct][r]);
        }
    __syncthreads();
    for (int i = tid; i < 1024; i += 256) {
        int lr = i >> 4, s = i & 15;
        uint4 v = *(const uint4*)&clds[lr * 128 + ((s ^ (lr & 7)) << 3)];
        ((uint4*)(outb + (size_t)(row0 + lr) * 64))[s] = v;
    }
}

// ---------------- D0: prep -- wt1/wt2 transpose (bf16), zero slots ----------------
__global__ __launch_bounds__(256) void k_prep(const float* __restrict__ W1, const float* __restrict__ W2,
                                              unsigned short* __restrict__ wt1, unsigned short* __restrict__ wt2,
                                              float* __restrict__ slots0) {
    int bid = blockIdx.x, tid = threadIdx.x;
    if (bid < 64) {                     // slots0: 2*64*256 = 32768 floats
        slots0[bid * 512 + tid] = 0.f;
        slots0[bid * 512 + 256 + tid] = 0.f;
    } else if (bid < 128) {             // wt1[c*128+k] = bf16(W1[k][c]); coalesced writes
        int i = (bid - 64) * 256 + tid;
        wt1[i] = (unsigned short)f_to_bf(W1[(i & 127) * 128 + (i >> 7)]);
    } else {                            // wt2 same
        int i = (bid - 128) * 256 + tid;
        wt2[i] = (unsigned short)f_to_bf(W2[(i & 127) * 128 + (i >> 7)]);
    }
}

// ---------------- D1: LDS-histogram count (atomic-free CSR metadata) + GEMM1 ----------------
// Block (c,oct) streams chunk c's dst (40KB, L2-hot), LDS-hists its 5120-node eighth,
// writes rank[e], degT[c][.] slice, window sums wsum[c][w]. GEMM1 blocks follow.
__global__ __launch_bounds__(256, 5) void k_countgemm(const int* __restrict__ dst,
                                                      int* __restrict__ degT, int* __restrict__ rank,
                                                      int* __restrict__ wsum,
                                                      const unsigned short* __restrict__ wt1,
                                                      const float* __restrict__ X, u32* __restrict__ outb) {
    __shared__ __align__(16) char sbuf[32768];   // hist (20480B) / gemm union
    int bid = blockIdx.x;
    int tid = threadIdx.x;
    if (bid < HISTB) {
        int c = bid >> 3, oct = bid & 7;
        int nlo = oct * QN;
        int* hist = (int*)sbuf;
        for (int i = tid; i < QN; i += 256) hist[i] = 0;
        __syncthreads();
        int ebase = c * ECH;
        const int4* dst4 = (const int4*)(dst + ebase);   // ECH=10000 = 2500 int4
        for (int i4 = tid; i4 < 2500; i4 += 256) {
            int4 d4 = dst4[i4];
            int e = ebase + i4 * 4;
            int t0 = d4.x - nlo, t1 = d4.y - nlo, t2 = d4.z - nlo, t3 = d4.w - nlo;
            if ((u32)t0 < (u32)QN) rank[e]     = atomicAdd(&hist[t0], 1);
            if ((u32)t1 < (u32)QN) rank[e + 1] = atomicAdd(&hist[t1], 1);
            if ((u32)t2 < (u32)QN) rank[e + 2] = atomicAdd(&hist[t2], 1);
            if ((u32)t3 < (u32)QN) rank[e + 3] = atomicAdd(&hist[t3], 1);
        }
        __syncthreads();
        // degT slice (coalesced, non-atomic)
        for (int i = tid; i < QN; i += 256) degT[(size_t)c * NPAD + nlo + i] = hist[i];
        // window sums: 20 windows x 256 entries
        int wv = tid >> 6, lane = tid & 63;
        for (int lw = wv; lw < 20; lw += 4) {
            int v = hist[lw * 256 + lane] + hist[lw * 256 + 64 + lane]
                  + hist[lw * 256 + 128 + lane] + hist[lw * 256 + 192 + lane];
            for (int off = 32; off > 0; off >>= 1) v += __shfl_down(v, off);
            if (lane == 0) wsum[c * NWIN + oct * 20 + lw] = v;
        }
        return;
    }
    gemm_core<false, false>(X, wt1, outb, nullptr, nullptr, nullptr,
                            bid - HISTB, sbuf, nullptr, nullptr);
}

// ---------------- D2: scan: 157 window blocks; base from wsum; emits row_ptr, dis, baseT ----------------
__global__ __launch_bounds__(256) void k_scan(const int* __restrict__ degT, const int* __restrict__ wsum,
                                              int* __restrict__ baseT,
                                              int* __restrict__ row_ptr, float* __restrict__ dis) {
    __shared__ int red[256];
    __shared__ int ls[256];
    int tid = threadIdx.x;
    int wnd = blockIdx.x;
    // cross-window base: sum wsum[c][w'] for all c, w' < wnd (incremental mod, no int-div)
    int part = 0;
    int wp = tid < NWIN ? tid : tid - NWIN;   // tid % 160 for tid<256
    for (int idx = tid; idx < NCHUNK * NWIN; idx += 256) {
        if (wp < wnd) part += wsum[idx];
        wp += 96; if (wp >= NWIN) wp -= NWIN;  // 256 mod 160 = 96
    }
    red[tid] = part;
    // per-node chunk prefix
    int n = wnd * 256 + tid;    // < 40192 < NPAD, safe
    int run = 0;
#pragma unroll 4
    for (int c = 0; c < NCHUNK; c++) {
        int v = degT[(size_t)c * NPAD + n];
        baseT[(size_t)c * NPAD + n] = run;
        run += v;
    }
    int d = run;
    ls[tid] = d;
    __syncthreads();
#pragma unroll
    for (int off = 128; off > 0; off >>= 1) {
        if (tid < off) red[tid] += red[tid + off];
        __syncthreads();
    }
    int base = red[0];
#pragma unroll
    for (int off = 1; off < 256; off <<= 1) {
        int t = (tid >= off) ? ls[tid - off] : 0;
        __syncthreads();
        ls[tid] += t;
        __syncthreads();
    }
    if (n < NN) {
        int r = base + ls[tid] - d;   // global exclusive prefix
        row_ptr[n] = r;
        dis[n] = rsqrtf((float)(d + 1));
    }
    if (wnd == NCH - 1 && tid == 0) row_ptr[NN] = NE;
}

// ---------------- D3: CSR fill: atomic-free; slot = row_ptr[d] + baseT[chunk][d] + rank[e] ----------------
__global__ __launch_bounds__(256) void k_fill(const int* __restrict__ src, const int* __restrict__ dst,
                                              const int* __restrict__ rank, const int* __restrict__ row_ptr,
                                              const int* __restrict__ baseT,
                                              const float* __restrict__ dis, u32* __restrict__ col) {
    int i4 = blockIdx.x * 256 + threadIdx.x;   // < 160000
    int4 d4 = ((const int4*)dst)[i4];
    int4 s4 = ((const int4*)src)[i4];
    int4 r4 = ((const int4*)rank)[i4];
    int e = i4 * 4;
    int dd[4] = {d4.x, d4.y, d4.z, d4.w};
    int ss[4] = {s4.x, s4.y, s4.z, s4.w};
    int rr[4] = {r4.x, r4.y, r4.z, r4.w};
#pragma unroll
    for (int q = 0; q < 4; q++) {
        int c = (e + q) / ECH;   // magic-mul, no HW div
        u32 h = (u32)__half_as_ushort(__float2half(dis[ss[q]]));
        col[row_ptr[dd[q]] + baseT[(size_t)c * NPAD + dd[q]] + rr[q]] = (u32)ss[q] | (h << 16);
    }
}

__global__ __launch_bounds__(256, 4) void k_gemm2(const u32* __restrict__ Hb, const unsigned short* __restrict__ wt2,
                                                  u32* __restrict__ outb, const float* __restrict__ slots,
                                                  const float* __restrict__ gam, const float* __restrict__ bet) {
    __shared__ __align__(16) char sbuf[32768];
    __shared__ float sc[128], sh[128];
    gemm_core<true, true>(Hb, wt2, outb, slots, gam, bet, blockIdx.x, sbuf, sc, sh);
}

// ---------------- GCN aggregation: one wave/node, 4 nodes/block; BN-stats fused ----------------
__global__ __launch_bounds__(256, 8) void k_gather(const u32* __restrict__ Hb, const int* __restrict__ row_ptr,
                                                   const u32* __restrict__ col, const float* __restrict__ dis,
                                                   const float* __restrict__ bias, u32* __restrict__ outb,
                                                   float* __restrict__ slots) {
    __shared__ float sred[4][128];
    __shared__ float qred[4][128];
    int t = threadIdx.x & 63;                       // lane: cols 2t, 2t+1
    int wv = threadIdx.x >> 6;
    int node = blockIdx.x * 4 + wv;
    float di = dis[node];
    int lo = row_ptr[node], hi = row_ptr[node + 1];
    float2 acc;
    {
        float2 a = bf2_to_f2(Hb[(size_t)node * 64 + t]);
        acc = make_float2(a.x * di, a.y * di);   // di factored: final acc *= di
    }
    for (int base = lo; base < hi; base += 64) {
        int m = hi - base; if (m > 64) m = 64;
        int cw = 0;
        if (t < m) cw = (int)col[base + t];
        int ng = (m + 3) >> 2;
        int c[4]; u32 u[4];
#pragma unroll
        for (int q = 0; q < 4; q++) {
            int idx = q < m ? q : 0;
            c[q] = __shfl(cw, idx);
            u[q] = Hb[(size_t)(c[q] & 0xffff) * 64 + t];
        }
        for (int g = 1; g < ng; g++) {
            int c2[4]; u32 u2[4];
#pragma unroll
            for (int q = 0; q < 4; q++) {
                int ii = g * 4 + q;
                int idx = ii < m ? ii : 0;
                c2[q] = __shfl(cw, idx);
                u2[q] = Hb[(size_t)(c2[q] & 0xffff) * 64 + t];
            }
#pragma unroll
            for (int q = 0; q < 4; q++) {
                int ii = (g - 1) * 4 + q;
                float wq = ii < m ? colw_to_f(c[q]) : 0.f;
                float2 h = bf2_to_f2(u[q]);
                acc.x = fmaf(h.x, wq, acc.x);
                acc.y = fmaf(h.y, wq, acc.y);
            }
#pragma unroll
            for (int q = 0; q < 4; q++) { c[q] = c2[q]; u[q] = u2[q]; }
        }
#pragma unroll
        for (int q = 0; q < 4; q++) {
            int ii = (ng - 1) * 4 + q;
            float wq = ii < m ? colw_to_f(c[q]) : 0.f;
            float2 h = bf2_to_f2(u[q]);
            acc.x = fmaf(h.x, wq, acc.x);
            acc.y = fmaf(h.y, wq, acc.y);
        }
    }
    float2 b = ((const float2*)bias)[t];
    acc.x = fmaf(acc.x, di, b.x);
    acc.y = fmaf(acc.y, di, b.y);
    outb[(size_t)node * 64 + t] = pack_bf2(acc.x, acc.y);
    // BN stats (pre-BN activations, incl. bias): block reduce -> 64-slot atomics
    sred[wv][2 * t] = acc.x;     sred[wv][2 * t + 1] = acc.y;
    qred[wv][2 * t] = acc.x * acc.x; qred[wv][2 * t + 1] = acc.y * acc.y;
    __syncthreads();
    int tid = threadIdx.x;
    if (tid < 128) {
        float s = sred[0][tid] + sred[1][tid] + sred[2][tid] + sred[3][tid];
        float q = qred[0][tid] + qred[1][tid] + qred[2][tid] + qred[3][tid];
        int slot = blockIdx.x & 63;
        atomicAdd(&slots[slot * 256 + tid], s);
        atomicAdd(&slots[slot * 256 + 128 + tid], q);
    }
}

// ---------------- pool (BN2+ReLU) + fc1 + fc2 + fc3, 4 graphs per block ----------------
__global__ __launch_bounds__(256) void k_poolfc(const u32* __restrict__ Hb, const int* __restrict__ batch,
                                                const float* __restrict__ slots,
                                                const float* __restrict__ gam, const float* __restrict__ bet,
                                                const float* __restrict__ fc1w, const float* __restrict__ fc1b,
                                                const float* __restrict__ fc2w, const float* __restrict__ fc2b,
                                                const float* __restrict__ fc3w, const float* __restrict__ fc3b,
                                                float* __restrict__ out) {
    __shared__ float sc[128], sh[128];
    __shared__ float pooled[4][128];
    __shared__ float g1[4][256];
    __shared__ float g2[4][256];
    __shared__ int bnds[5];
    int tid = threadIdx.x;
    int gbase = blockIdx.x * 4;
    if (tid < 128) {
        float s = 0.f, q = 0.f;
        for (int k = 0; k < 64; k++) {
            s += slots[k * 256 + tid];
            q += slots[k * 256 + 128 + tid];
        }
        const float inv_n = 1.0f / (float)NN;
        float mu = s * inv_n;
        float va = fmaf(-mu, mu, q * inv_n);
        float a = gam[tid] * rsqrtf(va + 1e-5f);
        sc[tid] = a;
        sh[tid] = fmaf(-mu, a, bet[tid]);
    } else if (tid < 133) {
        int target = gbase + (tid - 128);
        int a = 0, b = NN;
        while (a < b) { int m = (a + b) >> 1; if (batch[m] < target) a = m + 1; else b = m; }
        bnds[tid - 128] = a;
    }
    __syncthreads();
    {
        int g = tid >> 6, p = tid & 63;
        int lo = bnds[g], hi = bnds[g + 1];
        float a0 = 0.f, a1 = 0.f;
        float sc0 = sc[2 * p], sh0 = sh[2 * p], sc1 = sc[2 * p + 1], sh1 = sh[2 * p + 1];
        for (int i = lo; i < hi; i++) {
            float2 v = bf2_to_f2(Hb[(size_t)i * 64 + p]);
            a0 += fmaxf(fmaf(v.x, sc0, sh0), 0.f);
            a1 += fmaxf(fmaf(v.y, sc1, sh1), 0.f);
        }
        pooled[g][2 * p] = a0;
        pooled[g][2 * p + 1] = a1;
    }
    __syncthreads();
    {
        float x0 = 0.f, x1 = 0.f, x2 = 0.f, x3 = 0.f;
        for (int k = 0; k < 128; k++) {
            float wv = fc1w[k * 256 + tid];
            x0 = fmaf(pooled[0][k], wv, x0);
            x1 = fmaf(pooled[1][k], wv, x1);
            x2 = fmaf(pooled[2][k], wv, x2);
            x3 = fmaf(pooled[3][k], wv, x3);
        }
        float bb = fc1b[tid];
        g1[0][tid] = fmaxf(x0 + bb, 0.f);
        g1[1][tid] = fmaxf(x1 + bb, 0.f);
        g1[2][tid] = fmaxf(x2 + bb, 0.f);
        g1[3][tid] = fmaxf(x3 + bb, 0.f);
    }
    __syncthreads();
    {
        float x0 = 0.f, x1 = 0.f, x2 = 0.f, x3 = 0.f;
        for (int k = 0; k < 256; k++) {
            float wv = fc2w[k * 256 + tid];
            x0 = fmaf(g1[0][k], wv, x0);
            x1 = fmaf(g1[1][k], wv, x1);
            x2 = fmaf(g1[2][k], wv, x2);
            x3 = fmaf(g1[3][k], wv, x3);
        }
        float bb = fc2b[tid];
        g2[0][tid] = fmaxf(x0 + bb, 0.f);
        g2[1][tid] = fmaxf(x1 + bb, 0.f);
        g2[2][tid] = fmaxf(x2 + bb, 0.f);
        g2[3][tid] = fmaxf(x3 + bb, 0.f);
    }
    __syncthreads();
    {
        int lane = tid & 63, wv = tid >> 6;
        float s = fmaf(g2[wv][lane], fc3w[lane],
                  fmaf(g2[wv][64 + lane], fc3w[64 + lane],
                  fmaf(g2[wv][128 + lane], fc3w[128 + lane],
                       g2[wv][192 + lane] * fc3w[192 + lane])));
        for (int off = 32; off > 0; off >>= 1) s += __shfl_down(s, off);
        if (lane == 0) out[gbase + wv] = s + fc3b[0];
    }
}

extern "C" void kernel_launch(void* const* d_in, const int* in_sizes, int n_in,
                              void* d_out, int out_size, void* d_ws, size_t ws_size,
                              hipStream_t stream) {
    const float* x    = (const float*)d_in[0];
    const int*   ei   = (const int*)d_in[1];
    const int*   batch= (const int*)d_in[2];
    const float* W1   = (const float*)d_in[4];
    const float* b1   = (const float*)d_in[5];
    const float* W2   = (const float*)d_in[6];
    const float* b2   = (const float*)d_in[7];
    const float* bn1g = (const float*)d_in[8];
    const float* bn1b = (const float*)d_in[9];
    const float* bn2g = (const float*)d_in[10];
    const float* bn2b = (const float*)d_in[11];
    const float* fc1w = (const float*)d_in[12];
    const float* fc1b = (const float*)d_in[13];
    const float* fc2w = (const float*)d_in[14];
    const float* fc2b = (const float*)d_in[15];
    const float* fc3w = (const float*)d_in[16];
    const float* fc3b = (const float*)d_in[17];
    const int* src = ei;
    const int* dst = ei + NE;
    float* outp = (float*)d_out;

    char* w = (char*)d_ws;
    size_t o = 0;
    auto alloc = [&](size_t bytes) -> char* {
        char* p = w + o;
        o = (o + bytes + 255) & ~(size_t)255;
        return p;
    };
    int*   degT    = (int*)alloc((size_t)NCHUNK * NPAD * 4);   // written fully, no zeroing
    int*   baseT   = (int*)alloc((size_t)NCHUNK * NPAD * 4);
    int*   wsum    = (int*)alloc((size_t)NCHUNK * NWIN * 4);
    float* slots0  = (float*)alloc((size_t)2 * 64 * 256 * 4);  // zeroed in k_prep
    int*   row_ptr = (int*)alloc((size_t)(NN + 1) * 4);
    int*   rank    = (int*)alloc((size_t)NE * 4);
    u32*   col     = (u32*)alloc((size_t)NE * 4);
    float* dis     = (float*)alloc((size_t)NN * 4);
    unsigned short* wt1 = (unsigned short*)alloc(128 * 128 * 2);
    unsigned short* wt2 = (unsigned short*)alloc(128 * 128 * 2);
    u32*   bufA    = (u32*)alloc((size_t)NN * 64 * 4);
    u32*   bufB    = (u32*)alloc((size_t)NN * 64 * 4);
    float* slotsA  = slots0;
    float* slotsB  = slots0 + 64 * 256;

    k_prep<<<192, 256, 0, stream>>>(W1, W2, wt1, wt2, slots0);
    k_countgemm<<<HISTB + GT_BLKS, 256, 0, stream>>>(dst, degT, rank, wsum, wt1, x, bufA);
    k_scan<<<NCH, 256, 0, stream>>>(degT, wsum, baseT, row_ptr, dis);
    k_fill<<<FILLB, 256, 0, stream>>>(src, dst, rank, row_ptr, baseT, dis, col);
    k_gather<<<NN / 4, 256, 0, stream>>>(bufA, row_ptr, col, dis, b1, bufB, slotsA);
    k_gemm2<<<GT_BLKS, 256, 0, stream>>>(bufB, wt2, bufA, slotsA, bn1g, bn1b);
    k_gather<<<NN / 4, 256, 0, stream>>>(bufA, row_ptr, col, dis, b2, bufB, slotsB);
    k_poolfc<<<NG / 4, 256, 0, stream>>>(bufB, batch, slotsB, bn2g, bn2b,
                                         fc1w, fc1b, fc2w, fc2b, fc3w, fc3b, outp);
}

// Round 8
// 245.219 us; speedup vs baseline: 5.6700x; 1.0080x over previous
//
#include <hip/hip_runtime.h>
#include <hip/hip_fp16.h>

#define NN 40000
#define NE 640000
#define DF 128
#define NG 2000
#define NCH 157        // ceil(NN/256) node windows (256-node)
#define FILLB 625      // NE / (256*4) edge blocks, 4 edges/thread
#define GT_BLKS 625    // NN/64 -- 64-row GEMM tiles
#define NCHUNK 16      // edge chunks (was 64: smaller metadata -> baseT L2-resident in fill)
#define ECH 40000      // NE / NCHUNK
#define NOCT 8         // node eighths
#define QN 5120        // nodes per eighth (window-aligned: 20 windows of 256)
#define NPAD (NOCT * QN)   // 40960 padded nodes
#define NWIN 160       // NPAD / 256 windows
#define HISTB (NCHUNK * NOCT)  // 128 hist blocks (long-running; hide under GEMM1)

typedef unsigned int u32;
typedef __attribute__((ext_vector_type(8))) short short8;
typedef __attribute__((ext_vector_type(4))) float floatx4;

// ---- bf16 helpers (packed u32: low 16 = even col, high = odd col) ----
__device__ inline float2 bf2_to_f2(u32 u) {
    return make_float2(__uint_as_float(u << 16), __uint_as_float(u & 0xffff0000u));
}
__device__ inline u32 f_to_bf(float f) {
    u32 u = __float_as_uint(f);
    return (u + 0x7fffu + ((u >> 16) & 1u)) >> 16;   // RNE
}
__device__ inline u32 pack_bf2(float a, float b) {
    return f_to_bf(a) | (f_to_bf(b) << 16);
}
__device__ inline float bf_to_f(short s) {
    return __uint_as_float(((u32)(unsigned short)s) << 16);
}
// packed col entry: low 16 = src index (<65536), high 16 = fp16(dis[src])
__device__ inline float colw_to_f(int cw) {
    return __half2float(__ushort_as_half((unsigned short)((u32)cw >> 16)));
}

// ---------------- MFMA GEMM core, 64-row tile ----------------
// LDS sbuf = 32768 B: wlds = W^T bf16 [128 c][128 k], XOR-swizzled (16B chunk ^= row&7)
// -> stride 128, conflict-free. clds (C staging) same swizzle. Weights pre-transposed (k_prep).
template<bool BF16IN, bool FUSE_BN>
__device__ __forceinline__ void gemm_core(const void* __restrict__ Xv, const unsigned short* __restrict__ wt,
                                          u32* __restrict__ outb, const float* __restrict__ slots,
                                          const float* __restrict__ gam, const float* __restrict__ bet,
                                          int bid, char* sbuf, float* sc, float* sh) {
    unsigned short* wlds = (unsigned short*)sbuf;
    unsigned short* clds = (unsigned short*)sbuf;
    int tid = threadIdx.x;
    int row0 = bid * 64;

    if (FUSE_BN) {
        if (tid < 128) {
            float s = 0.f, q = 0.f;
            for (int k = 0; k < 64; k++) {
                s += slots[k * 256 + tid];
                q += slots[k * 256 + 128 + tid];
            }
            const float inv_n = 1.0f / (float)NN;
            float mu = s * inv_n;
            float va = fmaf(-mu, mu, q * inv_n);
            float a = gam[tid] * rsqrtf(va + 1e-5f);
            sc[tid] = a;
            sh[tid] = fmaf(-mu, a, bet[tid]);
        }
    }
    // stage W^T (pre-transposed bf16) into swizzled LDS: 8 uint4 per thread
    for (int i = tid; i < 2048; i += 256) {
        int c = i >> 4, s = i & 15;
        *(uint4*)&wlds[c * 128 + ((s ^ (c & 7)) << 3)] = ((const uint4*)wt)[i];
    }
    __syncthreads();

    int lane = tid & 63;
    int wave = tid >> 6;
    int qr = lane >> 4;
    int rl = lane & 15;

    int rA = row0 + wave * 16 + rl;   // < NN always (625*64 == NN)
    floatx4 acc[8];
#pragma unroll
    for (int b = 0; b < 8; b++) acc[b] = (floatx4){0.f, 0.f, 0.f, 0.f};
#pragma unroll
    for (int kb = 0; kb < 4; kb++) {
        int k0 = kb * 32 + qr * 8;
        short8 a0;
        if (!BF16IN) {
            const float* p0 = (const float*)Xv + (size_t)rA * DF + k0;
            float4 u0 = *(const float4*)p0, u1 = *(const float4*)(p0 + 4);
            float fa[8] = {u0.x, u0.y, u0.z, u0.w, u1.x, u1.y, u1.z, u1.w};
#pragma unroll
            for (int j = 0; j < 8; j++) a0[j] = (short)f_to_bf(fa[j]);
        } else {
            a0 = *(const short8*)((const u32*)Xv + (size_t)rA * 64 + (k0 >> 1));
            if (FUSE_BN) {
#pragma unroll
                for (int j = 0; j < 8; j++) {
                    float f0 = fmaxf(fmaf(bf_to_f(a0[j]), sc[k0 + j], sh[k0 + j]), 0.f);
                    a0[j] = (short)f_to_bf(f0);
                }
            }
        }
#pragma unroll
        for (int ct = 0; ct < 8; ct++) {
            int rowB = ct * 16 + rl;   // rowB&7 == rl&7
            short8 bfr = *(const short8*)&wlds[rowB * 128 + ((((kb << 2) + qr) ^ (rl & 7)) << 3)];
            acc[ct] = __builtin_amdgcn_mfma_f32_16x16x32_bf16(a0, bfr, acc[ct], 0, 0, 0);
        }
    }
    __syncthreads();
#pragma unroll
    for (int ct = 0; ct < 8; ct++)
#pragma unroll
        for (int r = 0; r < 4; r++) {
            int lr = wave * 16 + qr * 4 + r;
            int c = ct * 16 + rl;
            clds[lr * 128 + (((c >> 3) ^ (lr & 7)) << 3) + (c & 7)] = (unsigned short)f_to_bf(acc[ct][r]);
        }
    __syncthreads();
    for (int i = tid; i < 1024; i += 256) {
        int lr = i >> 4, s = i & 15;
        uint4 v = *(const uint4*)&clds[lr * 128 + ((s ^ (lr & 7)) << 3)];
        ((uint4*)(outb + (size_t)(row0 + lr) * 64))[s] = v;
    }
}

// ---------------- D0: prep -- wt1/wt2 transpose (bf16), zero slots ----------------
__global__ __launch_bounds__(256) void k_prep(const float* __restrict__ W1, const float* __restrict__ W2,
                                              unsigned short* __restrict__ wt1, unsigned short* __restrict__ wt2,
                                              float* __restrict__ slots0) {
    int bid = blockIdx.x, tid = threadIdx.x;
    if (bid < 64) {                     // slots0: 2*64*256 = 32768 floats
        slots0[bid * 512 + tid] = 0.f;
        slots0[bid * 512 + 256 + tid] = 0.f;
    } else if (bid < 128) {             // wt1[c*128+k] = bf16(W1[k][c]); coalesced writes
        int i = (bid - 64) * 256 + tid;
        wt1[i] = (unsigned short)f_to_bf(W1[(i & 127) * 128 + (i >> 7)]);
    } else {                            // wt2 same
        int i = (bid - 128) * 256 + tid;
        wt2[i] = (unsigned short)f_to_bf(W2[(i & 127) * 128 + (i >> 7)]);
    }
}

// ---------------- D1: LDS-histogram count (atomic-free CSR metadata) + GEMM1 ----------------
// Block (c,oct) streams chunk c's dst (160KB, L2-hot), LDS-hists its 5120-node eighth,
// writes rank[e], degT[c][.] slice, window sums wsum[c][w]. 128 long hist blocks hide
// under the 625 GEMM1 blocks in the same dispatch.
__global__ __launch_bounds__(256, 5) void k_countgemm(const int* __restrict__ dst,
                                                      int* __restrict__ degT, int* __restrict__ rank,
                                                      int* __restrict__ wsum,
                                                      const unsigned short* __restrict__ wt1,
                                                      const float* __restrict__ X, u32* __restrict__ outb) {
    __shared__ __align__(16) char sbuf[32768];   // hist (20480B) / gemm union
    int bid = blockIdx.x;
    int tid = threadIdx.x;
    if (bid < HISTB) {
        int c = bid >> 3, oct = bid & 7;
        int nlo = oct * QN;
        int* hist = (int*)sbuf;
        for (int i = tid; i < QN; i += 256) hist[i] = 0;
        __syncthreads();
        int ebase = c * ECH;
        const int4* dst4 = (const int4*)(dst + ebase);   // ECH=40000 = 10000 int4
        for (int i4 = tid; i4 < 10000; i4 += 256) {
            int4 d4 = dst4[i4];
            int e = ebase + i4 * 4;
            int t0 = d4.x - nlo, t1 = d4.y - nlo, t2 = d4.z - nlo, t3 = d4.w - nlo;
            if ((u32)t0 < (u32)QN) rank[e]     = atomicAdd(&hist[t0], 1);
            if ((u32)t1 < (u32)QN) rank[e + 1] = atomicAdd(&hist[t1], 1);
            if ((u32)t2 < (u32)QN) rank[e + 2] = atomicAdd(&hist[t2], 1);
            if ((u32)t3 < (u32)QN) rank[e + 3] = atomicAdd(&hist[t3], 1);
        }
        __syncthreads();
        // degT slice (coalesced, non-atomic)
        for (int i = tid; i < QN; i += 256) degT[(size_t)c * NPAD + nlo + i] = hist[i];
        // window sums: 20 windows x 256 entries
        int wv = tid >> 6, lane = tid & 63;
        for (int lw = wv; lw < 20; lw += 4) {
            int v = hist[lw * 256 + lane] + hist[lw * 256 + 64 + lane]
                  + hist[lw * 256 + 128 + lane] + hist[lw * 256 + 192 + lane];
            for (int off = 32; off > 0; off >>= 1) v += __shfl_down(v, off);
            if (lane == 0) wsum[c * NWIN + oct * 20 + lw] = v;
        }
        return;
    }
    gemm_core<false, false>(X, wt1, outb, nullptr, nullptr, nullptr,
                            bid - HISTB, sbuf, nullptr, nullptr);
}

// ---------------- D2: scan: 157 window blocks; base from wsum; emits row_ptr, dis, baseT ----------------
__global__ __launch_bounds__(256) void k_scan(const int* __restrict__ degT, const int* __restrict__ wsum,
                                              int* __restrict__ baseT,
                                              int* __restrict__ row_ptr, float* __restrict__ dis) {
    __shared__ int red[256];
    __shared__ int ls[256];
    int tid = threadIdx.x;
    int wnd = blockIdx.x;
    // cross-window base: sum wsum[c][w'] for all c, w' < wnd (incremental mod, no int-div)
    int part = 0;
    int wp = tid < NWIN ? tid : tid - NWIN;   // tid % 160 for tid<256
    for (int idx = tid; idx < NCHUNK * NWIN; idx += 256) {
        if (wp < wnd) part += wsum[idx];
        wp += 96; if (wp >= NWIN) wp -= NWIN;  // 256 mod 160 = 96
    }
    red[tid] = part;
    // per-node chunk prefix (16 iters, 2.6MB arrays: L2-friendly)
    int n = wnd * 256 + tid;    // < 40192 < NPAD, safe
    int run = 0;
#pragma unroll
    for (int c = 0; c < NCHUNK; c++) {
        int v = degT[(size_t)c * NPAD + n];
        baseT[(size_t)c * NPAD + n] = run;
        run += v;
    }
    int d = run;
    ls[tid] = d;
    __syncthreads();
#pragma unroll
    for (int off = 128; off > 0; off >>= 1) {
        if (tid < off) red[tid] += red[tid + off];
        __syncthreads();
    }
    int base = red[0];
#pragma unroll
    for (int off = 1; off < 256; off <<= 1) {
        int t = (tid >= off) ? ls[tid - off] : 0;
        __syncthreads();
        ls[tid] += t;
        __syncthreads();
    }
    if (n < NN) {
        int r = base + ls[tid] - d;   // global exclusive prefix
        row_ptr[n] = r;
        dis[n] = rsqrtf((float)(d + 1));
    }
    if (wnd == NCH - 1 && tid == 0) row_ptr[NN] = NE;
}

// ---------------- D3: CSR fill: atomic-free; slot = row_ptr[d] + baseT[chunk][d] + rank[e] ----------------
__global__ __launch_bounds__(256) void k_fill(const int* __restrict__ src, const int* __restrict__ dst,
                                              const int* __restrict__ rank, const int* __restrict__ row_ptr,
                                              const int* __restrict__ baseT,
                                              const float* __restrict__ dis, u32* __restrict__ col) {
    int i4 = blockIdx.x * 256 + threadIdx.x;   // < 160000
    int4 d4 = ((const int4*)dst)[i4];
    int4 s4 = ((const int4*)src)[i4];
    int4 r4 = ((const int4*)rank)[i4];
    int e = i4 * 4;
    int dd[4] = {d4.x, d4.y, d4.z, d4.w};
    int ss[4] = {s4.x, s4.y, s4.z, s4.w};
    int rr[4] = {r4.x, r4.y, r4.z, r4.w};
#pragma unroll
    for (int q = 0; q < 4; q++) {
        int c = (e + q) / ECH;   // magic-mul, no HW div
        u32 h = (u32)__half_as_ushort(__float2half(dis[ss[q]]));
        col[row_ptr[dd[q]] + baseT[(size_t)c * NPAD + dd[q]] + rr[q]] = (u32)ss[q] | (h << 16);
    }
}

__global__ __launch_bounds__(256, 4) void k_gemm2(const u32* __restrict__ Hb, const unsigned short* __restrict__ wt2,
                                                  u32* __restrict__ outb, const float* __restrict__ slots,
                                                  const float* __restrict__ gam, const float* __restrict__ bet) {
    __shared__ __align__(16) char sbuf[32768];
    __shared__ float sc[128], sh[128];
    gemm_core<true, true>(Hb, wt2, outb, slots, gam, bet, blockIdx.x, sbuf, sc, sh);
}

// ---------------- GCN aggregation: one wave/node, 4 nodes/block; BN-stats fused ----------------
__global__ __launch_bounds__(256, 8) void k_gather(const u32* __restrict__ Hb, const int* __restrict__ row_ptr,
                                                   const u32* __restrict__ col, const float* __restrict__ dis,
                                                   const float* __restrict__ bias, u32* __restrict__ outb,
                                                   float* __restrict__ slots) {
    __shared__ float sred[4][128];
    __shared__ float qred[4][128];
    int t = threadIdx.x & 63;                       // lane: cols 2t, 2t+1
    int wv = threadIdx.x >> 6;
    int node = blockIdx.x * 4 + wv;
    float di = dis[node];
    int lo = row_ptr[node], hi = row_ptr[node + 1];
    float2 acc;
    {
        float2 a = bf2_to_f2(Hb[(size_t)node * 64 + t]);
        acc = make_float2(a.x * di, a.y * di);   // di factored: final acc *= di
    }
    for (int base = lo; base < hi; base += 64) {
        int m = hi - base; if (m > 64) m = 64;
        int cw = 0;
        if (t < m) cw = (int)col[base + t];
        int ng = (m + 3) >> 2;
        int c[4]; u32 u[4];
#pragma unroll
        for (int q = 0; q < 4; q++) {
            int idx = q < m ? q : 0;
            c[q] = __shfl(cw, idx);
            u[q] = Hb[(size_t)(c[q] & 0xffff) * 64 + t];
        }
        for (int g = 1; g < ng; g++) {
            int c2[4]; u32 u2[4];
#pragma unroll
            for (int q = 0; q < 4; q++) {
                int ii = g * 4 + q;
                int idx = ii < m ? ii : 0;
                c2[q] = __shfl(cw, idx);
                u2[q] = Hb[(size_t)(c2[q] & 0xffff) * 64 + t];
            }
#pragma unroll
            for (int q = 0; q < 4; q++) {
                int ii = (g - 1) * 4 + q;
                float wq = ii < m ? colw_to_f(c[q]) : 0.f;
                float2 h = bf2_to_f2(u[q]);
                acc.x = fmaf(h.x, wq, acc.x);
                acc.y = fmaf(h.y, wq, acc.y);
            }
#pragma unroll
            for (int q = 0; q < 4; q++) { c[q] = c2[q]; u[q] = u2[q]; }
        }
#pragma unroll
        for (int q = 0; q < 4; q++) {
            int ii = (ng - 1) * 4 + q;
            float wq = ii < m ? colw_to_f(c[q]) : 0.f;
            float2 h = bf2_to_f2(u[q]);
            acc.x = fmaf(h.x, wq, acc.x);
            acc.y = fmaf(h.y, wq, acc.y);
        }
    }
    float2 b = ((const float2*)bias)[t];
    acc.x = fmaf(acc.x, di, b.x);
    acc.y = fmaf(acc.y, di, b.y);
    outb[(size_t)node * 64 + t] = pack_bf2(acc.x, acc.y);
    // BN stats (pre-BN activations, incl. bias): block reduce -> 64-slot atomics
    sred[wv][2 * t] = acc.x;     sred[wv][2 * t + 1] = acc.y;
    qred[wv][2 * t] = acc.x * acc.x; qred[wv][2 * t + 1] = acc.y * acc.y;
    __syncthreads();
    int tid = threadIdx.x;
    if (tid < 128) {
        float s = sred[0][tid] + sred[1][tid] + sred[2][tid] + sred[3][tid];
        float q = qred[0][tid] + qred[1][tid] + qred[2][tid] + qred[3][tid];
        int slot = blockIdx.x & 63;
        atomicAdd(&slots[slot * 256 + tid], s);
        atomicAdd(&slots[slot * 256 + 128 + tid], q);
    }
}

// ---------------- pool (BN2+ReLU) + fc1 + fc2 + fc3, 4 graphs per block ----------------
__global__ __launch_bounds__(256) void k_poolfc(const u32* __restrict__ Hb, const int* __restrict__ batch,
                                                const float* __restrict__ slots,
                                                const float* __restrict__ gam, const float* __restrict__ bet,
                                                const float* __restrict__ fc1w, const float* __restrict__ fc1b,
                                                const float* __restrict__ fc2w, const float* __restrict__ fc2b,
                                                const float* __restrict__ fc3w, const float* __restrict__ fc3b,
                                                float* __restrict__ out) {
    __shared__ float sc[128], sh[128];
    __shared__ float pooled[4][128];
    __shared__ float g1[4][256];
    __shared__ float g2[4][256];
    __shared__ int bnds[5];
    int tid = threadIdx.x;
    int gbase = blockIdx.x * 4;
    if (tid < 128) {
        float s = 0.f, q = 0.f;
        for (int k = 0; k < 64; k++) {
            s += slots[k * 256 + tid];
            q += slots[k * 256 + 128 + tid];
        }
        const float inv_n = 1.0f / (float)NN;
        float mu = s * inv_n;
        float va = fmaf(-mu, mu, q * inv_n);
        float a = gam[tid] * rsqrtf(va + 1e-5f);
        sc[tid] = a;
        sh[tid] = fmaf(-mu, a, bet[tid]);
    } else if (tid < 133) {
        int target = gbase + (tid - 128);
        int a = 0, b = NN;
        while (a < b) { int m = (a + b) >> 1; if (batch[m] < target) a = m + 1; else b = m; }
        bnds[tid - 128] = a;
    }
    __syncthreads();
    {
        int g = tid >> 6, p = tid & 63;
        int lo = bnds[g], hi = bnds[g + 1];
        float a0 = 0.f, a1 = 0.f;
        float sc0 = sc[2 * p], sh0 = sh[2 * p], sc1 = sc[2 * p + 1], sh1 = sh[2 * p + 1];
        for (int i = lo; i < hi; i++) {
            float2 v = bf2_to_f2(Hb[(size_t)i * 64 + p]);
            a0 += fmaxf(fmaf(v.x, sc0, sh0), 0.f);
            a1 += fmaxf(fmaf(v.y, sc1, sh1), 0.f);
        }
        pooled[g][2 * p] = a0;
        pooled[g][2 * p + 1] = a1;
    }
    __syncthreads();
    {
        float x0 = 0.f, x1 = 0.f, x2 = 0.f, x3 = 0.f;
        for (int k = 0; k < 128; k++) {
            float wv = fc1w[k * 256 + tid];
            x0 = fmaf(pooled[0][k], wv, x0);
            x1 = fmaf(pooled[1][k], wv, x1);
            x2 = fmaf(pooled[2][k], wv, x2);
            x3 = fmaf(pooled[3][k], wv, x3);
        }
        float bb = fc1b[tid];
        g1[0][tid] = fmaxf(x0 + bb, 0.f);
        g1[1][tid] = fmaxf(x1 + bb, 0.f);
        g1[2][tid] = fmaxf(x2 + bb, 0.f);
        g1[3][tid] = fmaxf(x3 + bb, 0.f);
    }
    __syncthreads();
    {
        float x0 = 0.f, x1 = 0.f, x2 = 0.f, x3 = 0.f;
        for (int k = 0; k < 256; k++) {
            float wv = fc2w[k * 256 + tid];
            x0 = fmaf(g1[0][k], wv, x0);
            x1 = fmaf(g1[1][k], wv, x1);
            x2 = fmaf(g1[2][k], wv, x2);
            x3 = fmaf(g1[3][k], wv, x3);
        }
        float bb = fc2b[tid];
        g2[0][tid] = fmaxf(x0 + bb, 0.f);
        g2[1][tid] = fmaxf(x1 + bb, 0.f);
        g2[2][tid] = fmaxf(x2 + bb, 0.f);
        g2[3][tid] = fmaxf(x3 + bb, 0.f);
    }
    __syncthreads();
    {
        int lane = tid & 63, wv = tid >> 6;
        float s = fmaf(g2[wv][lane], fc3w[lane],
                  fmaf(g2[wv][64 + lane], fc3w[64 + lane],
                  fmaf(g2[wv][128 + lane], fc3w[128 + lane],
                       g2[wv][192 + lane] * fc3w[192 + lane])));
        for (int off = 32; off > 0; off >>= 1) s += __shfl_down(s, off);
        if (lane == 0) out[gbase + wv] = s + fc3b[0];
    }
}

extern "C" void kernel_launch(void* const* d_in, const int* in_sizes, int n_in,
                              void* d_out, int out_size, void* d_ws, size_t ws_size,
                              hipStream_t stream) {
    const float* x    = (const float*)d_in[0];
    const int*   ei   = (const int*)d_in[1];
    const int*   batch= (const int*)d_in[2];
    const float* W1   = (const float*)d_in[4];
    const float* b1   = (const float*)d_in[5];
    const float* W2   = (const float*)d_in[6];
    const float* b2   = (const float*)d_in[7];
    const float* bn1g = (const float*)d_in[8];
    const float* bn1b = (const float*)d_in[9];
    const float* bn2g = (const float*)d_in[10];
    const float* bn2b = (const float*)d_in[11];
    const float* fc1w = (const float*)d_in[12];
    const float* fc1b = (const float*)d_in[13];
    const float* fc2w = (const float*)d_in[14];
    const float* fc2b = (const float*)d_in[15];
    const float* fc3w = (const float*)d_in[16];
    const float* fc3b = (const float*)d_in[17];
    const int* src = ei;
    const int* dst = ei + NE;
    float* outp = (float*)d_out;

    char* w = (char*)d_ws;
    size_t o = 0;
    auto alloc = [&](size_t bytes) -> char* {
        char* p = w + o;
        o = (o + bytes + 255) & ~(size_t)255;
        return p;
    };
    int*   degT    = (int*)alloc((size_t)NCHUNK * NPAD * 4);   // 2.6MB, written fully
    int*   baseT   = (int*)alloc((size_t)NCHUNK * NPAD * 4);   // 2.6MB -> L2-resident in fill
    int*   wsum    = (int*)alloc((size_t)NCHUNK * NWIN * 4);
    float* slots0  = (float*)alloc((size_t)2 * 64 * 256 * 4);  // zeroed in k_prep
    int*   row_ptr = (int*)alloc((size_t)(NN + 1) * 4);
    int*   rank    = (int*)alloc((size_t)NE * 4);
    u32*   col     = (u32*)alloc((size_t)NE * 4);
    float* dis     = (float*)alloc((size_t)NN * 4);
    unsigned short* wt1 = (unsigned short*)alloc(128 * 128 * 2);
    unsigned short* wt2 = (unsigned short*)alloc(128 * 128 * 2);
    u32*   bufA    = (u32*)alloc((size_t)NN * 64 * 4);
    u32*   bufB    = (u32*)alloc((size_t)NN * 64 * 4);
    float* slotsA  = slots0;
    float* slotsB  = slots0 + 64 * 256;

    k_prep<<<192, 256, 0, stream>>>(W1, W2, wt1, wt2, slots0);
    k_countgemm<<<HISTB + GT_BLKS, 256, 0, stream>>>(dst, degT, rank, wsum, wt1, x, bufA);
    k_scan<<<NCH, 256, 0, stream>>>(degT, wsum, baseT, row_ptr, dis);
    k_fill<<<FILLB, 256, 0, stream>>>(src, dst, rank, row_ptr, baseT, dis, col);
    k_gather<<<NN / 4, 256, 0, stream>>>(bufA, row_ptr, col, dis, b1, bufB, slotsA);
    k_gemm2<<<GT_BLKS, 256, 0, stream>>>(bufB, wt2, bufA, slotsA, bn1g, bn1b);
    k_gather<<<NN / 4, 256, 0, stream>>>(bufA, row_ptr, col, dis, b2, bufB, slotsB);
    k_poolfc<<<NG / 4, 256, 0, stream>>>(bufB, batch, slotsB, bn2g, bn2b,
                                         fc1w, fc1b, fc2w, fc2b, fc3w, fc3b, outp);
}